// Round 12
// baseline (530.571 us; speedup 1.0000x reference)
//
#include <hip/hip_runtime.h>

// Problem constants
#define BB 256
#define SS 512
#define DD 128

// fast sigmoid/tanh via v_rcp_f32 (approx rcp) — avoids IEEE division
__device__ __forceinline__ float sigf(float v) {
    return __builtin_amdgcn_rcpf(1.0f + __expf(-v));
}
__device__ __forceinline__ float tanhf_(float v) {
    return 1.0f - 2.0f * __builtin_amdgcn_rcpf(__expf(2.0f * v) + 1.0f);
}

// Barrier that waits ONLY on LDS ops (lgkmcnt): global prefetches stay in
// flight across it (r9 win). No sched_barrier (r11 win — lets the compiler
// hide prefetch issue under MFMA/ds_read shadows).
__device__ __forceinline__ void lds_barrier() {
    asm volatile("s_waitcnt lgkmcnt(0)" ::: "memory");
    __builtin_amdgcn_s_barrier();
}

typedef _Float16 f16x2 __attribute__((ext_vector_type(2)));
typedef _Float16 f16x8 __attribute__((ext_vector_type(8)));
typedef float    f32x4 __attribute__((ext_vector_type(4)));

#define MFMA16(A, B, C) __builtin_amdgcn_mfma_f32_16x16x32_f16((A), (B), (C), 0, 0, 0)

// ---------------------------------------------------------------------------
// Kernel P: f16 conversions: embeddings, WxT (transposed), Ws1T, Ws2T.
// ---------------------------------------------------------------------------
#define N_EQ  (20000 * 128)
#define N_EC  (2000 * 128)
#define N_EQD (101 * 128)
#define N_ECD (101 * 128)
#define N_WXT (512 * 128)
#define N_WS  (128 * 128)
#define N_CVT (N_EQ + N_EC + N_EQD + N_ECD + N_WXT + 2 * N_WS)

__global__ __launch_bounds__(256) void dimkt_cvt(
    const float* __restrict__ E_q, const float* __restrict__ E_c,
    const float* __restrict__ E_qd, const float* __restrict__ E_cd,
    const float* __restrict__ Wx,
    const float* __restrict__ W_s1, const float* __restrict__ W_s2,
    _Float16* __restrict__ E_qh, _Float16* __restrict__ E_ch,
    _Float16* __restrict__ E_qdh, _Float16* __restrict__ E_cdh,
    _Float16* __restrict__ WxTh,
    _Float16* __restrict__ Ws1T, _Float16* __restrict__ Ws2T)
{
    int o = blockIdx.x * 256 + threadIdx.x;
    if (o >= N_CVT) return;
    if (o < N_EQ) { E_qh[o] = (_Float16)E_q[o]; return; }
    o -= N_EQ;
    if (o < N_EC) { E_ch[o] = (_Float16)E_c[o]; return; }
    o -= N_EC;
    if (o < N_EQD) { E_qdh[o] = (_Float16)E_qd[o]; return; }
    o -= N_EQD;
    if (o < N_ECD) { E_cdh[o] = (_Float16)E_cd[o]; return; }
    o -= N_ECD;
    if (o < N_WXT) {                      // WxTh[n][k] = Wx[k][n], k<512, n<128
        int n = o >> 9, k = o & 511;
        WxTh[o] = (_Float16)Wx[k * 128 + n];
        return;
    }
    o -= N_WXT;
    if (o < N_WS) {                       // Ws1T[n][k] = W_s1[k][n]
        int n = o >> 7, k = o & 127;
        Ws1T[o] = (_Float16)W_s1[k * 128 + n];
        return;
    }
    o -= N_WS;
    {
        int n = o >> 7, k = o & 127;
        Ws2T[o] = (_Float16)W_s2[k * 128 + n];
    }
}

// ---------------------------------------------------------------------------
// Kernel A: precompute additive tables (fold corr/qd/cd embedding matmul parts)
// ---------------------------------------------------------------------------
__global__ void dimkt_tables(const float* __restrict__ E_corr,
                             const float* __restrict__ E_qd,
                             const float* __restrict__ E_cd,
                             const float* __restrict__ W_ki,
                             const float* __restrict__ W_p1,
                             const float* __restrict__ W_p2,
                             const float* __restrict__ b_ki,
                             const float* __restrict__ b_p1,
                             const float* __restrict__ b_p2,
                             float* __restrict__ Ck, float* __restrict__ Cp1,
                             float* __restrict__ Cp2, float* __restrict__ Qk,
                             float* __restrict__ Cdk)
{
    __shared__ float e[128];
    const int r = blockIdx.x;
    const int j = threadIdx.x;
    const float *emb, *W, *bias;
    float* op;
    if (r < 2)        { emb = E_corr + r * 128;        W = W_ki + 128 * 128; bias = b_ki;    op = Ck  + r * 128; }
    else if (r < 4)   { emb = E_corr + (r - 2) * 128;  W = W_p1 + 128 * 128; bias = b_p1;    op = Cp1 + (r - 2) * 128; }
    else if (r < 6)   { emb = E_corr + (r - 4) * 128;  W = W_p2 + 128 * 128; bias = b_p2;    op = Cp2 + (r - 4) * 128; }
    else if (r < 107) { emb = E_qd   + (r - 6) * 128;  W = W_ki + 256 * 128; bias = nullptr; op = Qk  + (r - 6) * 128; }
    else              { emb = E_cd   + (r - 107) * 128; W = W_ki + 384 * 128; bias = nullptr; op = Cdk + (r - 107) * 128; }
    e[j] = emb[j];
    __syncthreads();
    float acc = bias ? bias[j] : 0.0f;
#pragma unroll 8
    for (int i = 0; i < 128; ++i) acc = fmaf(e[i], W[i * 128 + j], acc);
    op[j] = acc;
}

// ---------------------------------------------------------------------------
// Kernel B: xh = (concat-gather @ Wx + bx) in f16, via f16 MFMA. No LDS.
// ---------------------------------------------------------------------------
__global__ __launch_bounds__(256, 2) void dimkt_xgemm(
    const int* __restrict__ q_seq, const int* __restrict__ c_seq,
    const int* __restrict__ qd_seq, const int* __restrict__ cd_seq,
    const _Float16* __restrict__ E_qh, const _Float16* __restrict__ E_ch,
    const _Float16* __restrict__ E_qdh, const _Float16* __restrict__ E_cdh,
    const _Float16* __restrict__ WxTh,
    const float* __restrict__ bx, _Float16* __restrict__ xh)
{
    const int tid = threadIdx.x;
    const int wv  = tid >> 6;
    const int l   = tid & 63;
    const int lm  = l & 15;
    const int kg8 = (l >> 4) * 8;
    const int m0  = blockIdx.x * 128;
    const int rbase = m0 + wv * 32;

    f32x4 acc0[8], acc1[8];
#pragma unroll
    for (int c = 0; c < 8; ++c) {
        acc0[c] = (f32x4){0.f, 0.f, 0.f, 0.f};
        acc1[c] = (f32x4){0.f, 0.f, 0.f, 0.f};
    }

#pragma unroll
    for (int s = 0; s < 4; ++s) {
        const _Float16* T  = (s == 0) ? E_qh : (s == 1) ? E_ch : (s == 2) ? E_qdh : E_cdh;
        const int*      sq = (s == 0) ? q_seq : (s == 1) ? c_seq : (s == 2) ? qd_seq : cd_seq;
        const int i0 = sq[rbase + lm];
        const int i1 = sq[rbase + 16 + lm];
        const _Float16* a0p = T + (size_t)i0 * 128 + kg8;
        const _Float16* a1p = T + (size_t)i1 * 128 + kg8;
#pragma unroll
        for (int kk = 0; kk < 4; ++kk) {
            const f16x8 a0 = *(const f16x8*)(a0p + kk * 32);
            const f16x8 a1 = *(const f16x8*)(a1p + kk * 32);
#pragma unroll
            for (int c = 0; c < 8; ++c) {
                const f16x8 bf = *(const f16x8*)&WxTh[(size_t)(c * 16 + lm) * 512
                                                      + s * 128 + kk * 32 + kg8];
                acc0[c] = MFMA16(a0, bf, acc0[c]);
                acc1[c] = MFMA16(a1, bf, acc1[c]);
            }
        }
    }

#pragma unroll
    for (int c = 0; c < 8; ++c) {
        const int col = c * 16 + lm;
        const float bxv = bx[col];
#pragma unroll
        for (int r = 0; r < 4; ++r) {
            const int row0 = rbase + (l >> 4) * 4 + r;
            xh[(size_t)row0 * 128 + col]        = (_Float16)(acc0[c][r] + bxv);
            xh[(size_t)(row0 + 16) * 128 + col] = (_Float16)(acc1[c][r] + bxv);
        }
    }
}

// ---------------------------------------------------------------------------
// Kernel B2: X1 = xh @ W_s1 + b_s1, X2 = xh @ W_s2 + b_s2 (f16 out).
// ---------------------------------------------------------------------------
__global__ __launch_bounds__(256, 2) void dimkt_x12(
    const _Float16* __restrict__ xh,
    const _Float16* __restrict__ Ws1T, const _Float16* __restrict__ Ws2T,
    const float* __restrict__ b_s1, const float* __restrict__ b_s2,
    _Float16* __restrict__ X1h, _Float16* __restrict__ X2h)
{
    const int tid = threadIdx.x;
    const int wv  = tid >> 6;
    const int l   = tid & 63;
    const int lm  = l & 15;
    const int kg8 = (l >> 4) * 8;
    const int rbase = blockIdx.x * 128 + wv * 32;

    f32x4 acc0[16], acc1[16];
#pragma unroll
    for (int c = 0; c < 16; ++c) {
        acc0[c] = (f32x4){0.f, 0.f, 0.f, 0.f};
        acc1[c] = (f32x4){0.f, 0.f, 0.f, 0.f};
    }

    const _Float16* a0p = xh + (size_t)(rbase + lm) * 128 + kg8;
    const _Float16* a1p = xh + (size_t)(rbase + 16 + lm) * 128 + kg8;
#pragma unroll
    for (int kk = 0; kk < 4; ++kk) {
        const f16x8 a0 = *(const f16x8*)(a0p + kk * 32);
        const f16x8 a1 = *(const f16x8*)(a1p + kk * 32);
#pragma unroll
        for (int c = 0; c < 16; ++c) {
            const _Float16* BT = (c < 8) ? Ws1T : Ws2T;
            const f16x8 bf = *(const f16x8*)&BT[(size_t)((c & 7) * 16 + lm) * 128
                                                + kk * 32 + kg8];
            acc0[c] = MFMA16(a0, bf, acc0[c]);
            acc1[c] = MFMA16(a1, bf, acc1[c]);
        }
    }

#pragma unroll
    for (int c = 0; c < 16; ++c) {
        const int col = (c & 7) * 16 + lm;
        const float bv = (c < 8) ? b_s1[col] : b_s2[col];
        _Float16* ob = (c < 8) ? X1h : X2h;
#pragma unroll
        for (int r = 0; r < 4; ++r) {
            const int row0 = rbase + (l >> 4) * 4 + r;
            ob[(size_t)row0 * 128 + col]        = (_Float16)(acc0[c][r] + bv);
            ob[(size_t)(row0 + 16) * 128 + col] = (_Float16)(acc1[c][r] + bv);
        }
    }
}

// ---------------------------------------------------------------------------
// helpers: load one B-fragment of a weight matrix (16x16x32 f16 MFMA),
// plain and negated (negation folds the a1 = X1 - h@Ws1 subtract into MFMA).
// ---------------------------------------------------------------------------
__device__ __forceinline__ f16x8 load_wfrag(const float* __restrict__ W,
                                            int kbase, int j) {
    f16x8 r;
#pragma unroll
    for (int e = 0; e < 8; ++e) r[e] = (_Float16)W[(kbase + e) * DD + j];
    return r;
}
__device__ __forceinline__ f16x8 load_wfrag_neg(const float* __restrict__ W,
                                                int kbase, int j) {
    f16x8 r;
#pragma unroll
    for (int e = 0; e < 8; ++e) r[e] = (_Float16)(-W[(kbase + e) * DD + j]);
    return r;
}

// ---------------------------------------------------------------------------
// Kernel C: sequential scan, v11 = v10 + prefetch placement fix.
//   r11 lesson: the table-prefetch block (5 loads + index chain, ~100-150cy
//   of VALU/VMEM issue) sat in the phase-2 region = on the pre-B2 critical
//   path (the barrier's "memory" clobber pins loads within their interval).
//   v11 moves table+index prefetch to loop-top (post-B2), where it hides
//   under phase-1's ds_read(120cy)+MFMA(190cy) shadow; X1/X2 prefetch keeps
//   its long lead in the phase-2 region (HBM latency). w1/w2 fragments are
//   negated at load so a1 = X1v + sum (subtract folded away).
// ---------------------------------------------------------------------------
__global__ __launch_bounds__(512, 2) void dimkt_scan(
    const _Float16* __restrict__ X1h, const _Float16* __restrict__ X2h,
    const int* __restrict__ corr_seq, const int* __restrict__ qd_seq,
    const int* __restrict__ cd_seq,
    const float* __restrict__ W_s1, const float* __restrict__ W_s2,
    const float* __restrict__ W_p1, const float* __restrict__ W_p2,
    const float* __restrict__ W_ki,
    const float* __restrict__ Ck, const float* __restrict__ Cp1,
    const float* __restrict__ Cp2, const float* __restrict__ Qk,
    const float* __restrict__ Cdk,
    const float* __restrict__ h0, _Float16* __restrict__ hb,
    float* __restrict__ out)
{
    __shared__ __align__(16) _Float16 h_h[128];
    __shared__ __align__(16) _Float16 s_h[128];

    const int tid  = threadIdx.x;
    const int b    = blockIdx.x;
    const int wv   = tid >> 6;
    const int l    = tid & 63;
    const int kgrp = l >> 4;
    const int j    = wv * 16 + (l & 15);
    const int base = b * SS;

    // --- 20 named weight B-fragments (w1/w2 negated) -------------------------
    const int kb = kgrp * 8;
    const f16x8 w1f0 = load_wfrag_neg(W_s1,  0 + kb, j);
    const f16x8 w1f1 = load_wfrag_neg(W_s1, 32 + kb, j);
    const f16x8 w1f2 = load_wfrag_neg(W_s1, 64 + kb, j);
    const f16x8 w1f3 = load_wfrag_neg(W_s1, 96 + kb, j);
    const f16x8 w2f0 = load_wfrag_neg(W_s2,  0 + kb, j);
    const f16x8 w2f1 = load_wfrag_neg(W_s2, 32 + kb, j);
    const f16x8 w2f2 = load_wfrag_neg(W_s2, 64 + kb, j);
    const f16x8 w2f3 = load_wfrag_neg(W_s2, 96 + kb, j);
    const f16x8 wkf0 = load_wfrag(W_ki,  0 + kb, j);
    const f16x8 wkf1 = load_wfrag(W_ki, 32 + kb, j);
    const f16x8 wkf2 = load_wfrag(W_ki, 64 + kb, j);
    const f16x8 wkf3 = load_wfrag(W_ki, 96 + kb, j);
    const f16x8 p1f0 = load_wfrag(W_p1,  0 + kb, j);
    const f16x8 p1f1 = load_wfrag(W_p1, 32 + kb, j);
    const f16x8 p1f2 = load_wfrag(W_p1, 64 + kb, j);
    const f16x8 p1f3 = load_wfrag(W_p1, 96 + kb, j);
    const f16x8 p2f0 = load_wfrag(W_p2,  0 + kb, j);
    const f16x8 p2f1 = load_wfrag(W_p2, 32 + kb, j);
    const f16x8 p2f2 = load_wfrag(W_p2, 64 + kb, j);
    const f16x8 p2f3 = load_wfrag(W_p2, 96 + kb, j);

    // --- init ----------------------------------------------------------------
    float h = h0[b * DD + j];
    if (kgrp == 0) h_h[j] = (_Float16)h;

    // step-0 tables (scalar indices)
    int ic = __builtin_amdgcn_readfirstlane(corr_seq[base]);
    int iq = __builtin_amdgcn_readfirstlane(qd_seq[base]);
    int ie = __builtin_amdgcn_readfirstlane(cd_seq[base]);
    float tck = Ck [ic * DD + j];
    float tqk = Qk [iq * DD + j];
    float tcd = Cdk[ie * DD + j];
    float tp1 = Cp1[ic * DD + j];
    float tp2 = Cp2[ic * DD + j];
    // indices for step 1 (pipelined)
    int icN = __builtin_amdgcn_readfirstlane(corr_seq[base + 1]);
    int iqN = __builtin_amdgcn_readfirstlane(qd_seq[base + 1]);
    int ieN = __builtin_amdgcn_readfirstlane(cd_seq[base + 1]);
    // X streams for step 0
    float X1v = (float)X1h[(size_t)base * DD + j];
    float X2v = (float)X2h[(size_t)base * DD + j];
    lds_barrier();

    const f32x4 z = {0.f, 0.f, 0.f, 0.f};

#pragma unroll 2
    for (int t = 0; t < 511; ++t) {
        // ---- loop-top prefetch (post-B2): tables(t+1) + indices(t+2). -------
        // Issue hides under phase-1 ds_read/MFMA latency; consumed next iter.
        float nck = Ck [icN * DD + j];
        float nqk = Qk [iqN * DD + j];
        float ncd = Cdk[ieN * DD + j];
        float np1 = Cp1[icN * DD + j];
        float np2 = Cp2[icN * DD + j];
        const int n2 = base + ((t + 2 > 511) ? 511 : (t + 2));
        int icN2 = __builtin_amdgcn_readfirstlane(corr_seq[n2]);
        int iqN2 = __builtin_amdgcn_readfirstlane(qd_seq[n2]);
        int ieN2 = __builtin_amdgcn_readfirstlane(cd_seq[n2]);

        // ---- phase 1: a1 = X1 - h@Ws1 (neg-folded), a2 likewise, kg = h@Wki -
        const f16x8 hA0 = *(const f16x8*)&h_h[ 0 + kb];
        const f16x8 hA1 = *(const f16x8*)&h_h[32 + kb];
        const f16x8 hA2 = *(const f16x8*)&h_h[64 + kb];
        const f16x8 hA3 = *(const f16x8*)&h_h[96 + kb];

        f32x4 c1a = MFMA16(hA0, w1f0, z);
        f32x4 c2a = MFMA16(hA0, w2f0, z);
        f32x4 cka = MFMA16(hA0, wkf0, z);
        f32x4 c1b = MFMA16(hA2, w1f2, z);
        f32x4 c2b = MFMA16(hA2, w2f2, z);
        f32x4 ckb = MFMA16(hA2, wkf2, z);
        c1a = MFMA16(hA1, w1f1, c1a);
        c2a = MFMA16(hA1, w2f1, c2a);
        cka = MFMA16(hA1, wkf1, cka);
        c1b = MFMA16(hA3, w1f3, c1b);
        c2b = MFMA16(hA3, w2f3, c2b);
        ckb = MFMA16(hA3, wkf3, ckb);

        float a1 = X1v + c1a[0] + c1b[0];        // weights negated at load
        float a2 = X2v + c2a[0] + c2b[0];
        float sdf = sigf(a1) * tanhf_(a2);
        if (kgrp == 0) s_h[j] = (_Float16)sdf;   // write ASAP
        float t3 = tck + tqk + tcd;              // hides under MFMA shadow
        float kg = cka[0] + ckb[0];
        lds_barrier();     // B1

        // ---- phase 2: p1 = sdf@Wp1, p2 = sdf@Wp2; h update ------------------
        const f16x8 sA0 = *(const f16x8*)&s_h[ 0 + kb];
        const f16x8 sA1 = *(const f16x8*)&s_h[32 + kb];
        const f16x8 sA2 = *(const f16x8*)&s_h[64 + kb];
        const f16x8 sA3 = *(const f16x8*)&s_h[96 + kb];

        f32x4 q1a = MFMA16(sA0, p1f0, z);
        f32x4 q2a = MFMA16(sA0, p2f0, z);
        f32x4 q1b = MFMA16(sA2, p1f2, z);
        f32x4 q2b = MFMA16(sA2, p2f2, z);
        q1a = MFMA16(sA1, p1f1, q1a);
        q2a = MFMA16(sA1, p2f1, q2a);
        q1b = MFMA16(sA3, p1f3, q1b);
        q2b = MFMA16(sA3, p2f3, q2b);

        // g's sigmoid here: trans issue hides under phase-2 MFMA latency
        float g = sigf(kg + t3);

        // ---- X-stream prefetch (t+1): long lead kept (HBM latency) ----------
        const size_t xoff = (size_t)(base + t + 1) * DD;
        float nX1 = (float)X1h[xoff + j];
        float nX2 = (float)X2h[xoff + j];

        float pka = sigf(q1a[0] + q1b[0] + tp1) * tanhf_(q2a[0] + q2b[0] + tp2);
        float hn  = fmaf(g, h - pka, pka);
        _Float16 hn16 = (_Float16)hn;
        if (kgrp == 0) {
            h_h[j] = hn16;                            // LDS write ASAP
            hb[(size_t)(base + t) * DD + j] = hn16;   // fire-and-forget store
        }

        h = hn;
        X1v = nX1; X2v = nX2;
        tck = nck; tqk = nqk; tcd = ncd; tp1 = np1; tp2 = np2;
        icN = icN2; iqN = iqN2; ieN = ieN2;
        lds_barrier();     // B2
    }

    if (tid == 0) out[base + 511] = 0.0f;
}

// ---------------------------------------------------------------------------
// Kernel D: y[b][t] = sigmoid(dot(xh[b][t+1], hb[b][t])), t = 0..510.
// ---------------------------------------------------------------------------
__global__ __launch_bounds__(256) void dimkt_y(
    const _Float16* __restrict__ xh, const _Float16* __restrict__ hb,
    float* __restrict__ out)
{
    const int o = blockIdx.x * 4 + (threadIdx.x >> 6);   // flat (b,t)
    const int l = threadIdx.x & 63;
    const int b = o >> 9;
    const int t = o & 511;
    if (t == 511) return;   // handled by scan
    f16x2 xv = *(const f16x2*)&xh[((size_t)(b * SS + t + 1)) * DD + 2 * l];
    f16x2 hv = *(const f16x2*)&hb[((size_t)(b * SS + t)) * DD + 2 * l];
    float s = (float)xv.x * (float)hv.x + (float)xv.y * (float)hv.y;
    s += __shfl_xor(s, 1);  s += __shfl_xor(s, 2);  s += __shfl_xor(s, 4);
    s += __shfl_xor(s, 8);  s += __shfl_xor(s, 16); s += __shfl_xor(s, 32);
    if (l == 0) out[b * SS + t] = sigf(s);
}

// ---------------------------------------------------------------------------
extern "C" void kernel_launch(void* const* d_in, const int* in_sizes, int n_in,
                              void* d_out, int out_size, void* d_ws, size_t ws_size,
                              hipStream_t stream) {
    const int*   q_seq    = (const int*)d_in[0];
    const int*   c_seq    = (const int*)d_in[1];
    const int*   qd_seq   = (const int*)d_in[2];
    const int*   cd_seq   = (const int*)d_in[3];
    const int*   corr_seq = (const int*)d_in[4];
    const float* E_q    = (const float*)d_in[5];
    const float* E_c    = (const float*)d_in[6];
    const float* E_qd   = (const float*)d_in[7];
    const float* E_cd   = (const float*)d_in[8];
    const float* E_corr = (const float*)d_in[9];
    const float* Wx     = (const float*)d_in[10];
    const float* bx     = (const float*)d_in[11];
    const float* W_s1   = (const float*)d_in[12];
    const float* b_s1   = (const float*)d_in[13];
    const float* W_s2   = (const float*)d_in[14];
    const float* b_s2   = (const float*)d_in[15];
    const float* W_p1   = (const float*)d_in[16];
    const float* b_p1   = (const float*)d_in[17];
    const float* W_p2   = (const float*)d_in[18];
    const float* b_p2   = (const float*)d_in[19];
    const float* W_ki   = (const float*)d_in[20];
    const float* b_ki   = (const float*)d_in[21];
    const float* h0     = (const float*)d_in[22];
    float* out = (float*)d_out;

    // ---- workspace carve-up -------------------------------------------------
    float* Ck   = (float*)d_ws;                       // 2 x 128
    float* Cp1  = Ck  + 256;
    float* Cp2  = Cp1 + 256;
    float* Qk   = Cp2 + 256;                          // 101 x 128
    float* Cdk  = Qk  + 101 * 128;                    // 101 x 128
    _Float16* pool  = (_Float16*)((char*)d_ws + (size_t)131072);
    const size_t NBT = (size_t)BB * SS * DD;          // 16,777,216
    _Float16* xh    = pool;                           // f16 x
    _Float16* X1h   = xh  + NBT;                      // f16 x@Ws1+b1
    _Float16* X2h   = X1h + NBT;                      // f16 x@Ws2+b2
    _Float16* hbuf  = X2h + NBT;                      // f16 h states
    _Float16* E_qh  = hbuf + NBT;
    _Float16* E_ch  = E_qh + N_EQ;
    _Float16* E_qdh = E_ch + N_EC;
    _Float16* E_cdh = E_qdh + N_EQD;
    _Float16* WxTh  = E_cdh + N_ECD;                  // 128 x 512 (transposed)
    _Float16* Ws1T  = WxTh + N_WXT;                   // 128 x 128 (transposed)
    _Float16* Ws2T  = Ws1T + N_WS;

    dimkt_cvt<<<(N_CVT + 255) / 256, 256, 0, stream>>>(
        E_q, E_c, E_qd, E_cd, Wx, W_s1, W_s2,
        E_qh, E_ch, E_qdh, E_cdh, WxTh, Ws1T, Ws2T);

    dimkt_tables<<<208, 128, 0, stream>>>(E_corr, E_qd, E_cd, W_ki, W_p1, W_p2,
                                          b_ki, b_p1, b_p2, Ck, Cp1, Cp2, Qk, Cdk);

    dimkt_xgemm<<<(BB * SS) / 128, 256, 0, stream>>>(q_seq, c_seq, qd_seq, cd_seq,
                                                     E_qh, E_ch, E_qdh, E_cdh,
                                                     WxTh, bx, xh);

    dimkt_x12<<<(BB * SS) / 128, 256, 0, stream>>>(xh, Ws1T, Ws2T, b_s1, b_s2,
                                                   X1h, X2h);

    dimkt_scan<<<BB, 512, 0, stream>>>(X1h, X2h, corr_seq, qd_seq, cd_seq,
                                       W_s1, W_s2, W_p1, W_p2, W_ki,
                                       Ck, Cp1, Cp2, Qk, Cdk, h0, hbuf, out);

    dimkt_y<<<(BB * SS) / 4, 256, 0, stream>>>(xh, hbuf, out);
}

// Round 13
// 521.281 us; speedup vs baseline: 1.0178x; 1.0178x over previous
//
#include <hip/hip_runtime.h>

// Problem constants
#define BB 256
#define SS 512
#define DD 128

// fast sigmoid/tanh via v_rcp_f32 (approx rcp) — avoids IEEE division
__device__ __forceinline__ float sigf(float v) {
    return __builtin_amdgcn_rcpf(1.0f + __expf(-v));
}
__device__ __forceinline__ float tanhf_(float v) {
    return 1.0f - 2.0f * __builtin_amdgcn_rcpf(__expf(2.0f * v) + 1.0f);
}

// Barrier that waits ONLY on LDS ops (lgkmcnt): global prefetches stay in
// flight across it (r9 win). No sched_barrier (r11 win).
__device__ __forceinline__ void lds_barrier() {
    asm volatile("s_waitcnt lgkmcnt(0)" ::: "memory");
    __builtin_amdgcn_s_barrier();
}

typedef _Float16 f16x2 __attribute__((ext_vector_type(2)));
typedef _Float16 f16x8 __attribute__((ext_vector_type(8)));
typedef float    f32x4 __attribute__((ext_vector_type(4)));

#define MFMA16(A, B, C) __builtin_amdgcn_mfma_f32_16x16x32_f16((A), (B), (C), 0, 0, 0)

// ---------------------------------------------------------------------------
// Kernel P: f16 conversions: embeddings, WxT (transposed), Ws1T, Ws2T.
// ---------------------------------------------------------------------------
#define N_EQ  (20000 * 128)
#define N_EC  (2000 * 128)
#define N_EQD (101 * 128)
#define N_ECD (101 * 128)
#define N_WXT (512 * 128)
#define N_WS  (128 * 128)
#define N_CVT (N_EQ + N_EC + N_EQD + N_ECD + N_WXT + 2 * N_WS)

__global__ __launch_bounds__(256) void dimkt_cvt(
    const float* __restrict__ E_q, const float* __restrict__ E_c,
    const float* __restrict__ E_qd, const float* __restrict__ E_cd,
    const float* __restrict__ Wx,
    const float* __restrict__ W_s1, const float* __restrict__ W_s2,
    _Float16* __restrict__ E_qh, _Float16* __restrict__ E_ch,
    _Float16* __restrict__ E_qdh, _Float16* __restrict__ E_cdh,
    _Float16* __restrict__ WxTh,
    _Float16* __restrict__ Ws1T, _Float16* __restrict__ Ws2T)
{
    int o = blockIdx.x * 256 + threadIdx.x;
    if (o >= N_CVT) return;
    if (o < N_EQ) { E_qh[o] = (_Float16)E_q[o]; return; }
    o -= N_EQ;
    if (o < N_EC) { E_ch[o] = (_Float16)E_c[o]; return; }
    o -= N_EC;
    if (o < N_EQD) { E_qdh[o] = (_Float16)E_qd[o]; return; }
    o -= N_EQD;
    if (o < N_ECD) { E_cdh[o] = (_Float16)E_cd[o]; return; }
    o -= N_ECD;
    if (o < N_WXT) {                      // WxTh[n][k] = Wx[k][n], k<512, n<128
        int n = o >> 9, k = o & 511;
        WxTh[o] = (_Float16)Wx[k * 128 + n];
        return;
    }
    o -= N_WXT;
    if (o < N_WS) {                       // Ws1T[n][k] = W_s1[k][n]
        int n = o >> 7, k = o & 127;
        Ws1T[o] = (_Float16)W_s1[k * 128 + n];
        return;
    }
    o -= N_WS;
    {
        int n = o >> 7, k = o & 127;
        Ws2T[o] = (_Float16)W_s2[k * 128 + n];
    }
}

// ---------------------------------------------------------------------------
// Kernel A: precompute additive tables (fold corr/qd/cd embedding matmul parts)
// ---------------------------------------------------------------------------
__global__ void dimkt_tables(const float* __restrict__ E_corr,
                             const float* __restrict__ E_qd,
                             const float* __restrict__ E_cd,
                             const float* __restrict__ W_ki,
                             const float* __restrict__ W_p1,
                             const float* __restrict__ W_p2,
                             const float* __restrict__ b_ki,
                             const float* __restrict__ b_p1,
                             const float* __restrict__ b_p2,
                             float* __restrict__ Ck, float* __restrict__ Cp1,
                             float* __restrict__ Cp2, float* __restrict__ Qk,
                             float* __restrict__ Cdk)
{
    __shared__ float e[128];
    const int r = blockIdx.x;
    const int j = threadIdx.x;
    const float *emb, *W, *bias;
    float* op;
    if (r < 2)        { emb = E_corr + r * 128;        W = W_ki + 128 * 128; bias = b_ki;    op = Ck  + r * 128; }
    else if (r < 4)   { emb = E_corr + (r - 2) * 128;  W = W_p1 + 128 * 128; bias = b_p1;    op = Cp1 + (r - 2) * 128; }
    else if (r < 6)   { emb = E_corr + (r - 4) * 128;  W = W_p2 + 128 * 128; bias = b_p2;    op = Cp2 + (r - 4) * 128; }
    else if (r < 107) { emb = E_qd   + (r - 6) * 128;  W = W_ki + 256 * 128; bias = nullptr; op = Qk  + (r - 6) * 128; }
    else              { emb = E_cd   + (r - 107) * 128; W = W_ki + 384 * 128; bias = nullptr; op = Cdk + (r - 107) * 128; }
    e[j] = emb[j];
    __syncthreads();
    float acc = bias ? bias[j] : 0.0f;
#pragma unroll 8
    for (int i = 0; i < 128; ++i) acc = fmaf(e[i], W[i * 128 + j], acc);
    op[j] = acc;
}

// ---------------------------------------------------------------------------
// Kernel S: stream precompute. kgb[b][t][j] = Ck[corr]+Qk[qd]+Cdk[cd] (f16);
// Cp12h[c][j] = {Cp1[c][j], Cp2[c][j]} (f16x2, 2 rows). Removes all index
// chasing + 3-way table gather from the scan (r12 lesson: that issue cost
// sits on the scan's critical path wherever it's placed).
// ---------------------------------------------------------------------------
__global__ __launch_bounds__(256) void dimkt_strm(
    const int* __restrict__ corr_seq, const int* __restrict__ qd_seq,
    const int* __restrict__ cd_seq,
    const float* __restrict__ Ck, const float* __restrict__ Qk,
    const float* __restrict__ Cdk,
    const float* __restrict__ Cp1, const float* __restrict__ Cp2,
    _Float16* __restrict__ kgb, f16x2* __restrict__ Cp12h)
{
    const int row = blockIdx.x * 2 + (threadIdx.x >> 7);   // flat (b*S + t)
    const int j   = threadIdx.x & 127;
    const int ic  = corr_seq[row];
    const int iq  = qd_seq[row];
    const int ie  = cd_seq[row];
    float v = Ck[ic * 128 + j] + Qk[iq * 128 + j] + Cdk[ie * 128 + j];
    kgb[(size_t)row * 128 + j] = (_Float16)v;
    if (blockIdx.x == 0) {
        int c = threadIdx.x >> 7, jj = threadIdx.x & 127;
        f16x2 t;
        t.x = (_Float16)Cp1[c * 128 + jj];
        t.y = (_Float16)Cp2[c * 128 + jj];
        Cp12h[c * 128 + jj] = t;
    }
}

// ---------------------------------------------------------------------------
// Kernel B: xh = (concat-gather @ Wx + bx) in f16, via f16 MFMA. No LDS.
// ---------------------------------------------------------------------------
__global__ __launch_bounds__(256, 2) void dimkt_xgemm(
    const int* __restrict__ q_seq, const int* __restrict__ c_seq,
    const int* __restrict__ qd_seq, const int* __restrict__ cd_seq,
    const _Float16* __restrict__ E_qh, const _Float16* __restrict__ E_ch,
    const _Float16* __restrict__ E_qdh, const _Float16* __restrict__ E_cdh,
    const _Float16* __restrict__ WxTh,
    const float* __restrict__ bx, _Float16* __restrict__ xh)
{
    const int tid = threadIdx.x;
    const int wv  = tid >> 6;
    const int l   = tid & 63;
    const int lm  = l & 15;
    const int kg8 = (l >> 4) * 8;
    const int m0  = blockIdx.x * 128;
    const int rbase = m0 + wv * 32;

    f32x4 acc0[8], acc1[8];
#pragma unroll
    for (int c = 0; c < 8; ++c) {
        acc0[c] = (f32x4){0.f, 0.f, 0.f, 0.f};
        acc1[c] = (f32x4){0.f, 0.f, 0.f, 0.f};
    }

#pragma unroll
    for (int s = 0; s < 4; ++s) {
        const _Float16* T  = (s == 0) ? E_qh : (s == 1) ? E_ch : (s == 2) ? E_qdh : E_cdh;
        const int*      sq = (s == 0) ? q_seq : (s == 1) ? c_seq : (s == 2) ? qd_seq : cd_seq;
        const int i0 = sq[rbase + lm];
        const int i1 = sq[rbase + 16 + lm];
        const _Float16* a0p = T + (size_t)i0 * 128 + kg8;
        const _Float16* a1p = T + (size_t)i1 * 128 + kg8;
#pragma unroll
        for (int kk = 0; kk < 4; ++kk) {
            const f16x8 a0 = *(const f16x8*)(a0p + kk * 32);
            const f16x8 a1 = *(const f16x8*)(a1p + kk * 32);
#pragma unroll
            for (int c = 0; c < 8; ++c) {
                const f16x8 bf = *(const f16x8*)&WxTh[(size_t)(c * 16 + lm) * 512
                                                      + s * 128 + kk * 32 + kg8];
                acc0[c] = MFMA16(a0, bf, acc0[c]);
                acc1[c] = MFMA16(a1, bf, acc1[c]);
            }
        }
    }

#pragma unroll
    for (int c = 0; c < 8; ++c) {
        const int col = c * 16 + lm;
        const float bxv = bx[col];
#pragma unroll
        for (int r = 0; r < 4; ++r) {
            const int row0 = rbase + (l >> 4) * 4 + r;
            xh[(size_t)row0 * 128 + col]        = (_Float16)(acc0[c][r] + bxv);
            xh[(size_t)(row0 + 16) * 128 + col] = (_Float16)(acc1[c][r] + bxv);
        }
    }
}

// ---------------------------------------------------------------------------
// Kernel B2: X12[b][t][j] = { xh@Ws1+b1, xh@Ws2+b2 } interleaved f16x2 —
// the scan reads one 4B load per step instead of two 2B loads.
// ---------------------------------------------------------------------------
__global__ __launch_bounds__(256, 2) void dimkt_x12(
    const _Float16* __restrict__ xh,
    const _Float16* __restrict__ Ws1T, const _Float16* __restrict__ Ws2T,
    const float* __restrict__ b_s1, const float* __restrict__ b_s2,
    f16x2* __restrict__ X12)
{
    const int tid = threadIdx.x;
    const int wv  = tid >> 6;
    const int l   = tid & 63;
    const int lm  = l & 15;
    const int kg8 = (l >> 4) * 8;
    const int rbase = blockIdx.x * 128 + wv * 32;

    f32x4 acc0[16], acc1[16];
#pragma unroll
    for (int c = 0; c < 16; ++c) {
        acc0[c] = (f32x4){0.f, 0.f, 0.f, 0.f};
        acc1[c] = (f32x4){0.f, 0.f, 0.f, 0.f};
    }

    const _Float16* a0p = xh + (size_t)(rbase + lm) * 128 + kg8;
    const _Float16* a1p = xh + (size_t)(rbase + 16 + lm) * 128 + kg8;
#pragma unroll
    for (int kk = 0; kk < 4; ++kk) {
        const f16x8 a0 = *(const f16x8*)(a0p + kk * 32);
        const f16x8 a1 = *(const f16x8*)(a1p + kk * 32);
#pragma unroll
        for (int c = 0; c < 16; ++c) {
            const _Float16* BT = (c < 8) ? Ws1T : Ws2T;
            const f16x8 bf = *(const f16x8*)&BT[(size_t)((c & 7) * 16 + lm) * 128
                                                + kk * 32 + kg8];
            acc0[c] = MFMA16(a0, bf, acc0[c]);
            acc1[c] = MFMA16(a1, bf, acc1[c]);
        }
    }

#pragma unroll
    for (int c = 0; c < 8; ++c) {
        const int col = c * 16 + lm;
        const float bv1 = b_s1[col];
        const float bv2 = b_s2[col];
#pragma unroll
        for (int r = 0; r < 4; ++r) {
            const int row0 = rbase + (l >> 4) * 4 + r;
            f16x2 v0, v1;
            v0.x = (_Float16)(acc0[c][r] + bv1);
            v0.y = (_Float16)(acc0[c + 8][r] + bv2);
            v1.x = (_Float16)(acc1[c][r] + bv1);
            v1.y = (_Float16)(acc1[c + 8][r] + bv2);
            X12[(size_t)row0 * 128 + col]        = v0;
            X12[(size_t)(row0 + 16) * 128 + col] = v1;
        }
    }
}

// ---------------------------------------------------------------------------
// helpers: load one B-fragment of a weight matrix (16x16x32 f16 MFMA),
// plain and negated (negation folds a1 = X1 - h@Ws1 into the MFMA sum).
// ---------------------------------------------------------------------------
__device__ __forceinline__ f16x8 load_wfrag(const float* __restrict__ W,
                                            int kbase, int j) {
    f16x8 r;
#pragma unroll
    for (int e = 0; e < 8; ++e) r[e] = (_Float16)W[(kbase + e) * DD + j];
    return r;
}
__device__ __forceinline__ f16x8 load_wfrag_neg(const float* __restrict__ W,
                                                int kbase, int j) {
    f16x8 r;
#pragma unroll
    for (int e = 0; e < 8; ++e) r[e] = (_Float16)(-W[(kbase + e) * DD + j]);
    return r;
}

// ---------------------------------------------------------------------------
// Kernel C: sequential scan, v12 — r11 base (best: 387us) + stream diet.
//   All table gathers/index chains replaced by sequential f16 streams
//   (kgb, X12) + one tiny Cp12h lookup keyed by the single pipelined corr
//   index. Per-step VMEM: 3 loads + 1 tiny + 1 store (was 8+). Prefetch
//   issue stays in the phase-2 region (r12 lesson: loop-top regressed).
// ---------------------------------------------------------------------------
__global__ __launch_bounds__(512, 2) void dimkt_scan(
    const f16x2* __restrict__ X12, const _Float16* __restrict__ kgb,
    const int* __restrict__ corr_seq, const f16x2* __restrict__ Cp12h,
    const float* __restrict__ W_s1, const float* __restrict__ W_s2,
    const float* __restrict__ W_p1, const float* __restrict__ W_p2,
    const float* __restrict__ W_ki,
    const float* __restrict__ h0, _Float16* __restrict__ hb,
    float* __restrict__ out)
{
    __shared__ __align__(16) _Float16 h_h[128];
    __shared__ __align__(16) _Float16 s_h[128];

    const int tid  = threadIdx.x;
    const int b    = blockIdx.x;
    const int wv   = tid >> 6;
    const int l    = tid & 63;
    const int kgrp = l >> 4;
    const int j    = wv * 16 + (l & 15);
    const int base = b * SS;

    // --- 20 named weight B-fragments (w1/w2 negated) -------------------------
    const int kb = kgrp * 8;
    const f16x8 w1f0 = load_wfrag_neg(W_s1,  0 + kb, j);
    const f16x8 w1f1 = load_wfrag_neg(W_s1, 32 + kb, j);
    const f16x8 w1f2 = load_wfrag_neg(W_s1, 64 + kb, j);
    const f16x8 w1f3 = load_wfrag_neg(W_s1, 96 + kb, j);
    const f16x8 w2f0 = load_wfrag_neg(W_s2,  0 + kb, j);
    const f16x8 w2f1 = load_wfrag_neg(W_s2, 32 + kb, j);
    const f16x8 w2f2 = load_wfrag_neg(W_s2, 64 + kb, j);
    const f16x8 w2f3 = load_wfrag_neg(W_s2, 96 + kb, j);
    const f16x8 wkf0 = load_wfrag(W_ki,  0 + kb, j);
    const f16x8 wkf1 = load_wfrag(W_ki, 32 + kb, j);
    const f16x8 wkf2 = load_wfrag(W_ki, 64 + kb, j);
    const f16x8 wkf3 = load_wfrag(W_ki, 96 + kb, j);
    const f16x8 p1f0 = load_wfrag(W_p1,  0 + kb, j);
    const f16x8 p1f1 = load_wfrag(W_p1, 32 + kb, j);
    const f16x8 p1f2 = load_wfrag(W_p1, 64 + kb, j);
    const f16x8 p1f3 = load_wfrag(W_p1, 96 + kb, j);
    const f16x8 p2f0 = load_wfrag(W_p2,  0 + kb, j);
    const f16x8 p2f1 = load_wfrag(W_p2, 32 + kb, j);
    const f16x8 p2f2 = load_wfrag(W_p2, 64 + kb, j);
    const f16x8 p2f3 = load_wfrag(W_p2, 96 + kb, j);

    // --- init ----------------------------------------------------------------
    float h = h0[b * DD + j];
    if (kgrp == 0) h_h[j] = (_Float16)h;

    // step-0 streams and corr index pipeline
    f16x2    X12v = X12[(size_t)base * DD + j];
    _Float16 kgt  = kgb[(size_t)base * DD + j];
    f16x2    cpv  = Cp12h[corr_seq[base] * DD + j];
    int icN = __builtin_amdgcn_readfirstlane(corr_seq[base + 1]);
    lds_barrier();

    const f32x4 z = {0.f, 0.f, 0.f, 0.f};

#pragma unroll 2
    for (int t = 0; t < 511; ++t) {
        // ---- phase 1: a1 = X1 - h@Ws1 (neg-folded), a2 likewise, kg = h@Wki -
        const f16x8 hA0 = *(const f16x8*)&h_h[ 0 + kb];
        const f16x8 hA1 = *(const f16x8*)&h_h[32 + kb];
        const f16x8 hA2 = *(const f16x8*)&h_h[64 + kb];
        const f16x8 hA3 = *(const f16x8*)&h_h[96 + kb];

        f32x4 c1a = MFMA16(hA0, w1f0, z);
        f32x4 c2a = MFMA16(hA0, w2f0, z);
        f32x4 cka = MFMA16(hA0, wkf0, z);
        f32x4 c1b = MFMA16(hA2, w1f2, z);
        f32x4 c2b = MFMA16(hA2, w2f2, z);
        f32x4 ckb = MFMA16(hA2, wkf2, z);
        c1a = MFMA16(hA1, w1f1, c1a);
        c2a = MFMA16(hA1, w2f1, c2a);
        cka = MFMA16(hA1, wkf1, cka);
        c1b = MFMA16(hA3, w1f3, c1b);
        c2b = MFMA16(hA3, w2f3, c2b);
        ckb = MFMA16(hA3, wkf3, ckb);

        float a1 = (float)X12v.x + c1a[0] + c1b[0];    // weights negated
        float a2 = (float)X12v.y + c2a[0] + c2b[0];
        float sdf = sigf(a1) * tanhf_(a2);
        if (kgrp == 0) s_h[j] = (_Float16)sdf;         // write ASAP
        float kg = cka[0] + ckb[0] + (float)kgt;
        lds_barrier();     // B1

        // ---- phase 2: p1 = sdf@Wp1, p2 = sdf@Wp2; h update ------------------
        const f16x8 sA0 = *(const f16x8*)&s_h[ 0 + kb];
        const f16x8 sA1 = *(const f16x8*)&s_h[32 + kb];
        const f16x8 sA2 = *(const f16x8*)&s_h[64 + kb];
        const f16x8 sA3 = *(const f16x8*)&s_h[96 + kb];

        f32x4 q1a = MFMA16(sA0, p1f0, z);
        f32x4 q2a = MFMA16(sA0, p2f0, z);
        f32x4 q1b = MFMA16(sA2, p1f2, z);
        f32x4 q2b = MFMA16(sA2, p2f2, z);
        q1a = MFMA16(sA1, p1f1, q1a);
        q2a = MFMA16(sA1, p2f1, q2a);
        q1b = MFMA16(sA3, p1f3, q1b);
        q2b = MFMA16(sA3, p2f3, q2b);

        // g's sigmoid: trans issue hides under phase-2 MFMA latency
        float g = sigf(kg);

        // ---- stream prefetch for t+1 (phase-2 region — r11 placement) ------
        const size_t noff = (size_t)(base + t + 1) * DD + j;
        f16x2    nX12 = X12[noff];
        _Float16 nkgt = kgb[noff];
        f16x2    ncp  = Cp12h[icN * DD + j];
        const int n2 = base + ((t + 2 > 511) ? 511 : (t + 2));
        int icN2 = __builtin_amdgcn_readfirstlane(corr_seq[n2]);

        float pka = sigf(q1a[0] + q1b[0] + (float)cpv.x)
                  * tanhf_(q2a[0] + q2b[0] + (float)cpv.y);
        float hn  = fmaf(g, h - pka, pka);
        _Float16 hn16 = (_Float16)hn;
        if (kgrp == 0) {
            h_h[j] = hn16;                            // LDS write ASAP
            hb[(size_t)(base + t) * DD + j] = hn16;   // fire-and-forget store
        }

        h = hn;
        X12v = nX12; kgt = nkgt; cpv = ncp; icN = icN2;
        lds_barrier();     // B2
    }

    if (tid == 0) out[base + 511] = 0.0f;
}

// ---------------------------------------------------------------------------
// Kernel D: y[b][t] = sigmoid(dot(xh[b][t+1], hb[b][t])), t = 0..510.
// ---------------------------------------------------------------------------
__global__ __launch_bounds__(256) void dimkt_y(
    const _Float16* __restrict__ xh, const _Float16* __restrict__ hb,
    float* __restrict__ out)
{
    const int o = blockIdx.x * 4 + (threadIdx.x >> 6);   // flat (b,t)
    const int l = threadIdx.x & 63;
    const int b = o >> 9;
    const int t = o & 511;
    if (t == 511) return;   // handled by scan
    f16x2 xv = *(const f16x2*)&xh[((size_t)(b * SS + t + 1)) * DD + 2 * l];
    f16x2 hv = *(const f16x2*)&hb[((size_t)(b * SS + t)) * DD + 2 * l];
    float s = (float)xv.x * (float)hv.x + (float)xv.y * (float)hv.y;
    s += __shfl_xor(s, 1);  s += __shfl_xor(s, 2);  s += __shfl_xor(s, 4);
    s += __shfl_xor(s, 8);  s += __shfl_xor(s, 16); s += __shfl_xor(s, 32);
    if (l == 0) out[b * SS + t] = sigf(s);
}

// ---------------------------------------------------------------------------
extern "C" void kernel_launch(void* const* d_in, const int* in_sizes, int n_in,
                              void* d_out, int out_size, void* d_ws, size_t ws_size,
                              hipStream_t stream) {
    const int*   q_seq    = (const int*)d_in[0];
    const int*   c_seq    = (const int*)d_in[1];
    const int*   qd_seq   = (const int*)d_in[2];
    const int*   cd_seq   = (const int*)d_in[3];
    const int*   corr_seq = (const int*)d_in[4];
    const float* E_q    = (const float*)d_in[5];
    const float* E_c    = (const float*)d_in[6];
    const float* E_qd   = (const float*)d_in[7];
    const float* E_cd   = (const float*)d_in[8];
    const float* E_corr = (const float*)d_in[9];
    const float* Wx     = (const float*)d_in[10];
    const float* bx     = (const float*)d_in[11];
    const float* W_s1   = (const float*)d_in[12];
    const float* b_s1   = (const float*)d_in[13];
    const float* W_s2   = (const float*)d_in[14];
    const float* b_s2   = (const float*)d_in[15];
    const float* W_p1   = (const float*)d_in[16];
    const float* b_p1   = (const float*)d_in[17];
    const float* W_p2   = (const float*)d_in[18];
    const float* b_p2   = (const float*)d_in[19];
    const float* W_ki   = (const float*)d_in[20];
    const float* b_ki   = (const float*)d_in[21];
    const float* h0     = (const float*)d_in[22];
    float* out = (float*)d_out;

    // ---- workspace carve-up -------------------------------------------------
    float* Ck   = (float*)d_ws;                       // 2 x 128
    float* Cp1  = Ck  + 256;
    float* Cp2  = Cp1 + 256;
    float* Qk   = Cp2 + 256;                          // 101 x 128
    float* Cdk  = Qk  + 101 * 128;                    // 101 x 128
    _Float16* pool  = (_Float16*)((char*)d_ws + (size_t)131072);
    const size_t NBT = (size_t)BB * SS * DD;          // 16,777,216
    _Float16* xh    = pool;                           // f16 x          (32MB)
    f16x2*    X12   = (f16x2*)(xh + NBT);             // {X1,X2} f16x2  (64MB)
    _Float16* hbuf  = (_Float16*)(X12 + NBT);         // f16 h states   (32MB)
    _Float16* kgb   = hbuf + NBT;                     // kg table strm  (32MB)
    f16x2*    Cp12h = (f16x2*)(kgb + NBT);            // 2 x 128 f16x2
    _Float16* E_qh  = (_Float16*)(Cp12h + 256);
    _Float16* E_ch  = E_qh + N_EQ;
    _Float16* E_qdh = E_ch + N_EC;
    _Float16* E_cdh = E_qdh + N_EQD;
    _Float16* WxTh  = E_cdh + N_ECD;                  // 128 x 512 (transposed)
    _Float16* Ws1T  = WxTh + N_WXT;                   // 128 x 128 (transposed)
    _Float16* Ws2T  = Ws1T + N_WS;

    dimkt_cvt<<<(N_CVT + 255) / 256, 256, 0, stream>>>(
        E_q, E_c, E_qd, E_cd, Wx, W_s1, W_s2,
        E_qh, E_ch, E_qdh, E_cdh, WxTh, Ws1T, Ws2T);

    dimkt_tables<<<208, 128, 0, stream>>>(E_corr, E_qd, E_cd, W_ki, W_p1, W_p2,
                                          b_ki, b_p1, b_p2, Ck, Cp1, Cp2, Qk, Cdk);

    dimkt_strm<<<(BB * SS) / 2, 256, 0, stream>>>(corr_seq, qd_seq, cd_seq,
                                                  Ck, Qk, Cdk, Cp1, Cp2,
                                                  kgb, Cp12h);

    dimkt_xgemm<<<(BB * SS) / 128, 256, 0, stream>>>(q_seq, c_seq, qd_seq, cd_seq,
                                                     E_qh, E_ch, E_qdh, E_cdh,
                                                     WxTh, bx, xh);

    dimkt_x12<<<(BB * SS) / 128, 256, 0, stream>>>(xh, Ws1T, Ws2T, b_s1, b_s2,
                                                   X12);

    dimkt_scan<<<BB, 512, 0, stream>>>(X12, kgb, corr_seq, Cp12h,
                                       W_s1, W_s2, W_p1, W_p2, W_ki,
                                       h0, hbuf, out);

    dimkt_y<<<(BB * SS) / 4, 256, 0, stream>>>(xh, hbuf, out);
}

// Round 14
// 489.079 us; speedup vs baseline: 1.0848x; 1.0658x over previous
//
#include <hip/hip_runtime.h>

// Problem constants
#define BB 256
#define SS 512
#define DD 128

// fast sigmoid/tanh via v_rcp_f32 (approx rcp) — avoids IEEE division
__device__ __forceinline__ float sigf(float v) {
    return __builtin_amdgcn_rcpf(1.0f + __expf(-v));
}
__device__ __forceinline__ float tanhf_(float v) {
    return 1.0f - 2.0f * __builtin_amdgcn_rcpf(__expf(2.0f * v) + 1.0f);
}

// Barrier that waits ONLY on LDS ops (lgkmcnt): global prefetches stay in
// flight across it (r9 win). No sched_barrier (r11 win).
__device__ __forceinline__ void lds_barrier() {
    asm volatile("s_waitcnt lgkmcnt(0)" ::: "memory");
    __builtin_amdgcn_s_barrier();
}

typedef _Float16 f16x2 __attribute__((ext_vector_type(2)));
typedef _Float16 f16x8 __attribute__((ext_vector_type(8)));
typedef float    f32x4 __attribute__((ext_vector_type(4)));

#define MFMA16(A, B, C) __builtin_amdgcn_mfma_f32_16x16x32_f16((A), (B), (C), 0, 0, 0)

// ---------------------------------------------------------------------------
// Kernel P: f16 conversions: embeddings, WxT (transposed), Ws1T, Ws2T.
// ---------------------------------------------------------------------------
#define N_EQ  (20000 * 128)
#define N_EC  (2000 * 128)
#define N_EQD (101 * 128)
#define N_ECD (101 * 128)
#define N_WXT (512 * 128)
#define N_WS  (128 * 128)
#define N_CVT (N_EQ + N_EC + N_EQD + N_ECD + N_WXT + 2 * N_WS)

__global__ __launch_bounds__(256) void dimkt_cvt(
    const float* __restrict__ E_q, const float* __restrict__ E_c,
    const float* __restrict__ E_qd, const float* __restrict__ E_cd,
    const float* __restrict__ Wx,
    const float* __restrict__ W_s1, const float* __restrict__ W_s2,
    _Float16* __restrict__ E_qh, _Float16* __restrict__ E_ch,
    _Float16* __restrict__ E_qdh, _Float16* __restrict__ E_cdh,
    _Float16* __restrict__ WxTh,
    _Float16* __restrict__ Ws1T, _Float16* __restrict__ Ws2T)
{
    int o = blockIdx.x * 256 + threadIdx.x;
    if (o >= N_CVT) return;
    if (o < N_EQ) { E_qh[o] = (_Float16)E_q[o]; return; }
    o -= N_EQ;
    if (o < N_EC) { E_ch[o] = (_Float16)E_c[o]; return; }
    o -= N_EC;
    if (o < N_EQD) { E_qdh[o] = (_Float16)E_qd[o]; return; }
    o -= N_EQD;
    if (o < N_ECD) { E_cdh[o] = (_Float16)E_cd[o]; return; }
    o -= N_ECD;
    if (o < N_WXT) {                      // WxTh[n][k] = Wx[k][n], k<512, n<128
        int n = o >> 9, k = o & 511;
        WxTh[o] = (_Float16)Wx[k * 128 + n];
        return;
    }
    o -= N_WXT;
    if (o < N_WS) {                       // Ws1T[n][k] = W_s1[k][n]
        int n = o >> 7, k = o & 127;
        Ws1T[o] = (_Float16)W_s1[k * 128 + n];
        return;
    }
    o -= N_WS;
    {
        int n = o >> 7, k = o & 127;
        Ws2T[o] = (_Float16)W_s2[k * 128 + n];
    }
}

// ---------------------------------------------------------------------------
// Kernel A: precompute additive tables (fold corr/qd/cd embedding matmul parts)
// ---------------------------------------------------------------------------
__global__ void dimkt_tables(const float* __restrict__ E_corr,
                             const float* __restrict__ E_qd,
                             const float* __restrict__ E_cd,
                             const float* __restrict__ W_ki,
                             const float* __restrict__ W_p1,
                             const float* __restrict__ W_p2,
                             const float* __restrict__ b_ki,
                             const float* __restrict__ b_p1,
                             const float* __restrict__ b_p2,
                             float* __restrict__ Ck, float* __restrict__ Cp1,
                             float* __restrict__ Cp2, float* __restrict__ Qk,
                             float* __restrict__ Cdk)
{
    __shared__ float e[128];
    const int r = blockIdx.x;
    const int j = threadIdx.x;
    const float *emb, *W, *bias;
    float* op;
    if (r < 2)        { emb = E_corr + r * 128;        W = W_ki + 128 * 128; bias = b_ki;    op = Ck  + r * 128; }
    else if (r < 4)   { emb = E_corr + (r - 2) * 128;  W = W_p1 + 128 * 128; bias = b_p1;    op = Cp1 + (r - 2) * 128; }
    else if (r < 6)   { emb = E_corr + (r - 4) * 128;  W = W_p2 + 128 * 128; bias = b_p2;    op = Cp2 + (r - 4) * 128; }
    else if (r < 107) { emb = E_qd   + (r - 6) * 128;  W = W_ki + 256 * 128; bias = nullptr; op = Qk  + (r - 6) * 128; }
    else              { emb = E_cd   + (r - 107) * 128; W = W_ki + 384 * 128; bias = nullptr; op = Cdk + (r - 107) * 128; }
    e[j] = emb[j];
    __syncthreads();
    float acc = bias ? bias[j] : 0.0f;
#pragma unroll 8
    for (int i = 0; i < 128; ++i) acc = fmaf(e[i], W[i * 128 + j], acc);
    op[j] = acc;
}

// ---------------------------------------------------------------------------
// Kernel S: kgb[b][t][j] = Ck[corr]+Qk[qd]+Cdk[cd] (f16 stream).
//   Grid-stride, f16x2 stores (r13's one-value-per-thread 65536-block version
//   was dispatch-inefficient).
// ---------------------------------------------------------------------------
__global__ __launch_bounds__(256) void dimkt_strm2(
    const int* __restrict__ corr_seq, const int* __restrict__ qd_seq,
    const int* __restrict__ cd_seq,
    const float* __restrict__ Ck, const float* __restrict__ Qk,
    const float* __restrict__ Cdk,
    _Float16* __restrict__ kgb)
{
    const int total = BB * SS * 64;          // f16x2 elements
    for (int v = blockIdx.x * 256 + threadIdx.x; v < total; v += 2048 * 256) {
        const int row = v >> 6;              // flat (b*S + t)
        const int j2  = (v & 63) * 2;
        const int ic  = corr_seq[row];
        const int iq  = qd_seq[row];
        const int ie  = cd_seq[row];
        f16x2 o;
        o.x = (_Float16)(Ck[ic * 128 + j2]     + Qk[iq * 128 + j2]     + Cdk[ie * 128 + j2]);
        o.y = (_Float16)(Ck[ic * 128 + j2 + 1] + Qk[iq * 128 + j2 + 1] + Cdk[ie * 128 + j2 + 1]);
        *(f16x2*)&kgb[(size_t)row * 128 + j2] = o;
    }
}

// ---------------------------------------------------------------------------
// Kernel F: FUSED feed = xgemm + x12 (r13 lesson: x12's 32MB xh re-read and
// the extra launch are pure waste — each block computes a full 128x128 xh
// tile with complete K, so the second GEMM can run off an LDS tile).
//   Stage A: xh tile via MFMA from gathered f16 embeddings; write xh (for y)
//            and stash in padded LDS (stride 136 f16 -> <=2-way aliasing).
//   Stage B: X1 = xh@Ws1+b1, X2 = xh@Ws2+b2 with A-frags from LDS; write
//            interleaved X12 f16x2.
// ---------------------------------------------------------------------------
__global__ __launch_bounds__(256, 2) void dimkt_feed(
    const int* __restrict__ q_seq, const int* __restrict__ c_seq,
    const int* __restrict__ qd_seq, const int* __restrict__ cd_seq,
    const _Float16* __restrict__ E_qh, const _Float16* __restrict__ E_ch,
    const _Float16* __restrict__ E_qdh, const _Float16* __restrict__ E_cdh,
    const _Float16* __restrict__ WxTh, const float* __restrict__ bx,
    const _Float16* __restrict__ Ws1T, const _Float16* __restrict__ Ws2T,
    const float* __restrict__ b_s1, const float* __restrict__ b_s2,
    _Float16* __restrict__ xh, f16x2* __restrict__ X12)
{
    __shared__ _Float16 xt[128][136];        // padded: 272B row stride

    const int tid = threadIdx.x;
    const int wv  = tid >> 6;
    const int l   = tid & 63;
    const int lm  = l & 15;
    const int kg8 = (l >> 4) * 8;
    const int m0  = blockIdx.x * 128;
    const int rbase = m0 + wv * 32;

    // ---- stage A: xh tile --------------------------------------------------
    {
        f32x4 acc0[8], acc1[8];
#pragma unroll
        for (int c = 0; c < 8; ++c) {
            acc0[c] = (f32x4){0.f, 0.f, 0.f, 0.f};
            acc1[c] = (f32x4){0.f, 0.f, 0.f, 0.f};
        }
#pragma unroll
        for (int s = 0; s < 4; ++s) {
            const _Float16* T  = (s == 0) ? E_qh : (s == 1) ? E_ch : (s == 2) ? E_qdh : E_cdh;
            const int*      sq = (s == 0) ? q_seq : (s == 1) ? c_seq : (s == 2) ? qd_seq : cd_seq;
            const int i0 = sq[rbase + lm];
            const int i1 = sq[rbase + 16 + lm];
            const _Float16* a0p = T + (size_t)i0 * 128 + kg8;
            const _Float16* a1p = T + (size_t)i1 * 128 + kg8;
#pragma unroll
            for (int kk = 0; kk < 4; ++kk) {
                const f16x8 a0 = *(const f16x8*)(a0p + kk * 32);
                const f16x8 a1 = *(const f16x8*)(a1p + kk * 32);
#pragma unroll
                for (int c = 0; c < 8; ++c) {
                    const f16x8 bf = *(const f16x8*)&WxTh[(size_t)(c * 16 + lm) * 512
                                                          + s * 128 + kk * 32 + kg8];
                    acc0[c] = MFMA16(a0, bf, acc0[c]);
                    acc1[c] = MFMA16(a1, bf, acc1[c]);
                }
            }
        }
#pragma unroll
        for (int c = 0; c < 8; ++c) {
            const int col = c * 16 + lm;
            const float bxv = bx[col];
#pragma unroll
            for (int r = 0; r < 4; ++r) {
                const int lr = wv * 32 + (l >> 4) * 4 + r;   // local row
                _Float16 v0 = (_Float16)(acc0[c][r] + bxv);
                _Float16 v1 = (_Float16)(acc1[c][r] + bxv);
                xh[(size_t)(m0 + lr) * 128 + col]      = v0;
                xh[(size_t)(m0 + lr + 16) * 128 + col] = v1;
                xt[lr][col]      = v0;
                xt[lr + 16][col] = v1;
            }
        }
    }
    __syncthreads();

    // ---- stage B: X1/X2 from the LDS tile ----------------------------------
    {
        f32x4 acc0[16], acc1[16];
#pragma unroll
        for (int c = 0; c < 16; ++c) {
            acc0[c] = (f32x4){0.f, 0.f, 0.f, 0.f};
            acc1[c] = (f32x4){0.f, 0.f, 0.f, 0.f};
        }
#pragma unroll
        for (int kk = 0; kk < 4; ++kk) {
            const f16x8 a0 = *(const f16x8*)&xt[wv * 32 + lm][kk * 32 + kg8];
            const f16x8 a1 = *(const f16x8*)&xt[wv * 32 + 16 + lm][kk * 32 + kg8];
#pragma unroll
            for (int c = 0; c < 16; ++c) {
                const _Float16* BT = (c < 8) ? Ws1T : Ws2T;
                const f16x8 bf = *(const f16x8*)&BT[(size_t)((c & 7) * 16 + lm) * 128
                                                    + kk * 32 + kg8];
                acc0[c] = MFMA16(a0, bf, acc0[c]);
                acc1[c] = MFMA16(a1, bf, acc1[c]);
            }
        }
#pragma unroll
        for (int c = 0; c < 8; ++c) {
            const int col = c * 16 + lm;
            const float bv1 = b_s1[col];
            const float bv2 = b_s2[col];
#pragma unroll
            for (int r = 0; r < 4; ++r) {
                const int row0 = rbase + (l >> 4) * 4 + r;
                f16x2 v0, v1;
                v0.x = (_Float16)(acc0[c][r] + bv1);
                v0.y = (_Float16)(acc0[c + 8][r] + bv2);
                v1.x = (_Float16)(acc1[c][r] + bv1);
                v1.y = (_Float16)(acc1[c + 8][r] + bv2);
                X12[(size_t)row0 * 128 + col]        = v0;
                X12[(size_t)(row0 + 16) * 128 + col] = v1;
            }
        }
    }
}

// ---------------------------------------------------------------------------
// helpers: load one B-fragment of a weight matrix (16x16x32 f16 MFMA),
// plain and negated (negation folds a1 = X1 - h@Ws1 into the MFMA sum).
// ---------------------------------------------------------------------------
__device__ __forceinline__ f16x8 load_wfrag(const float* __restrict__ W,
                                            int kbase, int j) {
    f16x8 r;
#pragma unroll
    for (int e = 0; e < 8; ++e) r[e] = (_Float16)W[(kbase + e) * DD + j];
    return r;
}
__device__ __forceinline__ f16x8 load_wfrag_neg(const float* __restrict__ W,
                                                int kbase, int j) {
    f16x8 r;
#pragma unroll
    for (int e = 0; e < 8; ++e) r[e] = (_Float16)(-W[(kbase + e) * DD + j]);
    return r;
}

// ---------------------------------------------------------------------------
// Kernel C: sequential scan, v13 = r13 (356us best) + Cp register-select.
//   Cp1/Cp2 have only 2 rows (corr in {0,1}); r13's per-step gather + address
//   mul is replaced by 4 prologue-loaded f32 regs + 2 cndmask on the already-
//   pipelined corr scalar. Everything else frozen.
// ---------------------------------------------------------------------------
__global__ __launch_bounds__(512, 2) void dimkt_scan(
    const f16x2* __restrict__ X12, const _Float16* __restrict__ kgb,
    const int* __restrict__ corr_seq,
    const float* __restrict__ Cp1f, const float* __restrict__ Cp2f,
    const float* __restrict__ W_s1, const float* __restrict__ W_s2,
    const float* __restrict__ W_p1, const float* __restrict__ W_p2,
    const float* __restrict__ W_ki,
    const float* __restrict__ h0, _Float16* __restrict__ hb,
    float* __restrict__ out)
{
    __shared__ __align__(16) _Float16 h_h[128];
    __shared__ __align__(16) _Float16 s_h[128];

    const int tid  = threadIdx.x;
    const int b    = blockIdx.x;
    const int wv   = tid >> 6;
    const int l    = tid & 63;
    const int kgrp = l >> 4;
    const int j    = wv * 16 + (l & 15);
    const int base = b * SS;

    // --- 20 named weight B-fragments (w1/w2 negated) -------------------------
    const int kb = kgrp * 8;
    const f16x8 w1f0 = load_wfrag_neg(W_s1,  0 + kb, j);
    const f16x8 w1f1 = load_wfrag_neg(W_s1, 32 + kb, j);
    const f16x8 w1f2 = load_wfrag_neg(W_s1, 64 + kb, j);
    const f16x8 w1f3 = load_wfrag_neg(W_s1, 96 + kb, j);
    const f16x8 w2f0 = load_wfrag_neg(W_s2,  0 + kb, j);
    const f16x8 w2f1 = load_wfrag_neg(W_s2, 32 + kb, j);
    const f16x8 w2f2 = load_wfrag_neg(W_s2, 64 + kb, j);
    const f16x8 w2f3 = load_wfrag_neg(W_s2, 96 + kb, j);
    const f16x8 wkf0 = load_wfrag(W_ki,  0 + kb, j);
    const f16x8 wkf1 = load_wfrag(W_ki, 32 + kb, j);
    const f16x8 wkf2 = load_wfrag(W_ki, 64 + kb, j);
    const f16x8 wkf3 = load_wfrag(W_ki, 96 + kb, j);
    const f16x8 p1f0 = load_wfrag(W_p1,  0 + kb, j);
    const f16x8 p1f1 = load_wfrag(W_p1, 32 + kb, j);
    const f16x8 p1f2 = load_wfrag(W_p1, 64 + kb, j);
    const f16x8 p1f3 = load_wfrag(W_p1, 96 + kb, j);
    const f16x8 p2f0 = load_wfrag(W_p2,  0 + kb, j);
    const f16x8 p2f1 = load_wfrag(W_p2, 32 + kb, j);
    const f16x8 p2f2 = load_wfrag(W_p2, 64 + kb, j);
    const f16x8 p2f3 = load_wfrag(W_p2, 96 + kb, j);

    // --- Cp register residence (2 rows only) ---------------------------------
    const float cp1r0 = Cp1f[j],       cp2r0 = Cp2f[j];
    const float cp1r1 = Cp1f[128 + j], cp2r1 = Cp2f[128 + j];

    // --- init ----------------------------------------------------------------
    float h = h0[b * DD + j];
    if (kgrp == 0) h_h[j] = (_Float16)h;

    f16x2    X12v = X12[(size_t)base * DD + j];
    _Float16 kgt  = kgb[(size_t)base * DD + j];
    int ic0 = __builtin_amdgcn_readfirstlane(corr_seq[base]);
    float tcp1 = ic0 ? cp1r1 : cp1r0;
    float tcp2 = ic0 ? cp2r1 : cp2r0;
    int icN = __builtin_amdgcn_readfirstlane(corr_seq[base + 1]);
    lds_barrier();

    const f32x4 z = {0.f, 0.f, 0.f, 0.f};

#pragma unroll 2
    for (int t = 0; t < 511; ++t) {
        // ---- phase 1: a1 = X1 - h@Ws1 (neg-folded), a2 likewise, kg = h@Wki -
        const f16x8 hA0 = *(const f16x8*)&h_h[ 0 + kb];
        const f16x8 hA1 = *(const f16x8*)&h_h[32 + kb];
        const f16x8 hA2 = *(const f16x8*)&h_h[64 + kb];
        const f16x8 hA3 = *(const f16x8*)&h_h[96 + kb];

        f32x4 c1a = MFMA16(hA0, w1f0, z);
        f32x4 c2a = MFMA16(hA0, w2f0, z);
        f32x4 cka = MFMA16(hA0, wkf0, z);
        f32x4 c1b = MFMA16(hA2, w1f2, z);
        f32x4 c2b = MFMA16(hA2, w2f2, z);
        f32x4 ckb = MFMA16(hA2, wkf2, z);
        c1a = MFMA16(hA1, w1f1, c1a);
        c2a = MFMA16(hA1, w2f1, c2a);
        cka = MFMA16(hA1, wkf1, cka);
        c1b = MFMA16(hA3, w1f3, c1b);
        c2b = MFMA16(hA3, w2f3, c2b);
        ckb = MFMA16(hA3, wkf3, ckb);

        float a1 = (float)X12v.x + c1a[0] + c1b[0];    // weights negated
        float a2 = (float)X12v.y + c2a[0] + c2b[0];
        float sdf = sigf(a1) * tanhf_(a2);
        if (kgrp == 0) s_h[j] = (_Float16)sdf;         // write ASAP
        float kg = cka[0] + ckb[0] + (float)kgt;
        lds_barrier();     // B1

        // ---- phase 2: p1 = sdf@Wp1, p2 = sdf@Wp2; h update ------------------
        const f16x8 sA0 = *(const f16x8*)&s_h[ 0 + kb];
        const f16x8 sA1 = *(const f16x8*)&s_h[32 + kb];
        const f16x8 sA2 = *(const f16x8*)&s_h[64 + kb];
        const f16x8 sA3 = *(const f16x8*)&s_h[96 + kb];

        f32x4 q1a = MFMA16(sA0, p1f0, z);
        f32x4 q2a = MFMA16(sA0, p2f0, z);
        f32x4 q1b = MFMA16(sA2, p1f2, z);
        f32x4 q2b = MFMA16(sA2, p2f2, z);
        q1a = MFMA16(sA1, p1f1, q1a);
        q2a = MFMA16(sA1, p2f1, q2a);
        q1b = MFMA16(sA3, p1f3, q1b);
        q2b = MFMA16(sA3, p2f3, q2b);

        // g's sigmoid: trans issue hides under phase-2 MFMA latency
        float g = sigf(kg);

        // ---- stream prefetch for t+1 (phase-2 region — r11/r12 placement) --
        const size_t noff = (size_t)(base + t + 1) * DD + j;
        f16x2    nX12 = X12[noff];
        _Float16 nkgt = kgb[noff];
        float ncp1 = icN ? cp1r1 : cp1r0;
        float ncp2 = icN ? cp2r1 : cp2r0;
        const int n2 = base + ((t + 2 > 511) ? 511 : (t + 2));
        int icN2 = __builtin_amdgcn_readfirstlane(corr_seq[n2]);

        float pka = sigf(q1a[0] + q1b[0] + tcp1)
                  * tanhf_(q2a[0] + q2b[0] + tcp2);
        float hn  = fmaf(g, h - pka, pka);
        _Float16 hn16 = (_Float16)hn;
        if (kgrp == 0) {
            h_h[j] = hn16;                            // LDS write ASAP
            hb[(size_t)(base + t) * DD + j] = hn16;   // fire-and-forget store
        }

        h = hn;
        X12v = nX12; kgt = nkgt; tcp1 = ncp1; tcp2 = ncp2; icN = icN2;
        lds_barrier();     // B2
    }

    if (tid == 0) out[base + 511] = 0.0f;
}

// ---------------------------------------------------------------------------
// Kernel D: y[b][t] = sigmoid(dot(xh[b][t+1], hb[b][t])), t = 0..510.
// ---------------------------------------------------------------------------
__global__ __launch_bounds__(256) void dimkt_y(
    const _Float16* __restrict__ xh, const _Float16* __restrict__ hb,
    float* __restrict__ out)
{
    const int o = blockIdx.x * 4 + (threadIdx.x >> 6);   // flat (b,t)
    const int l = threadIdx.x & 63;
    const int b = o >> 9;
    const int t = o & 511;
    if (t == 511) return;   // handled by scan
    f16x2 xv = *(const f16x2*)&xh[((size_t)(b * SS + t + 1)) * DD + 2 * l];
    f16x2 hv = *(const f16x2*)&hb[((size_t)(b * SS + t)) * DD + 2 * l];
    float s = (float)xv.x * (float)hv.x + (float)xv.y * (float)hv.y;
    s += __shfl_xor(s, 1);  s += __shfl_xor(s, 2);  s += __shfl_xor(s, 4);
    s += __shfl_xor(s, 8);  s += __shfl_xor(s, 16); s += __shfl_xor(s, 32);
    if (l == 0) out[b * SS + t] = sigf(s);
}

// ---------------------------------------------------------------------------
extern "C" void kernel_launch(void* const* d_in, const int* in_sizes, int n_in,
                              void* d_out, int out_size, void* d_ws, size_t ws_size,
                              hipStream_t stream) {
    const int*   q_seq    = (const int*)d_in[0];
    const int*   c_seq    = (const int*)d_in[1];
    const int*   qd_seq   = (const int*)d_in[2];
    const int*   cd_seq   = (const int*)d_in[3];
    const int*   corr_seq = (const int*)d_in[4];
    const float* E_q    = (const float*)d_in[5];
    const float* E_c    = (const float*)d_in[6];
    const float* E_qd   = (const float*)d_in[7];
    const float* E_cd   = (const float*)d_in[8];
    const float* E_corr = (const float*)d_in[9];
    const float* Wx     = (const float*)d_in[10];
    const float* bx     = (const float*)d_in[11];
    const float* W_s1   = (const float*)d_in[12];
    const float* b_s1   = (const float*)d_in[13];
    const float* W_s2   = (const float*)d_in[14];
    const float* b_s2   = (const float*)d_in[15];
    const float* W_p1   = (const float*)d_in[16];
    const float* b_p1   = (const float*)d_in[17];
    const float* W_p2   = (const float*)d_in[18];
    const float* b_p2   = (const float*)d_in[19];
    const float* W_ki   = (const float*)d_in[20];
    const float* b_ki   = (const float*)d_in[21];
    const float* h0     = (const float*)d_in[22];
    float* out = (float*)d_out;

    // ---- workspace carve-up (same budget as r13) ----------------------------
    float* Ck   = (float*)d_ws;                       // 2 x 128
    float* Cp1  = Ck  + 256;
    float* Cp2  = Cp1 + 256;
    float* Qk   = Cp2 + 256;                          // 101 x 128
    float* Cdk  = Qk  + 101 * 128;                    // 101 x 128
    _Float16* pool  = (_Float16*)((char*)d_ws + (size_t)131072);
    const size_t NBT = (size_t)BB * SS * DD;          // 16,777,216
    _Float16* xh    = pool;                           // f16 x          (32MB)
    f16x2*    X12   = (f16x2*)(xh + NBT);             // {X1,X2} f16x2  (64MB)
    _Float16* hbuf  = (_Float16*)(X12 + NBT);         // f16 h states   (32MB)
    _Float16* kgb   = hbuf + NBT;                     // kg table strm  (32MB)
    _Float16* E_qh  = kgb + NBT;
    _Float16* E_ch  = E_qh + N_EQ;
    _Float16* E_qdh = E_ch + N_EC;
    _Float16* E_cdh = E_qdh + N_EQD;
    _Float16* WxTh  = E_cdh + N_ECD;                  // 128 x 512 (transposed)
    _Float16* Ws1T  = WxTh + N_WXT;                   // 128 x 128 (transposed)
    _Float16* Ws2T  = Ws1T + N_WS;

    dimkt_cvt<<<(N_CVT + 255) / 256, 256, 0, stream>>>(
        E_q, E_c, E_qd, E_cd, Wx, W_s1, W_s2,
        E_qh, E_ch, E_qdh, E_cdh, WxTh, Ws1T, Ws2T);

    dimkt_tables<<<208, 128, 0, stream>>>(E_corr, E_qd, E_cd, W_ki, W_p1, W_p2,
                                          b_ki, b_p1, b_p2, Ck, Cp1, Cp2, Qk, Cdk);

    dimkt_strm2<<<2048, 256, 0, stream>>>(corr_seq, qd_seq, cd_seq,
                                          Ck, Qk, Cdk, kgb);

    dimkt_feed<<<(BB * SS) / 128, 256, 0, stream>>>(
        q_seq, c_seq, qd_seq, cd_seq,
        E_qh, E_ch, E_qdh, E_cdh, WxTh, bx,
        Ws1T, Ws2T, b_s1, b_s2, xh, X12);

    dimkt_scan<<<BB, 512, 0, stream>>>(X12, kgb, corr_seq, Cp1, Cp2,
                                       W_s1, W_s2, W_p1, W_p2, W_ki,
                                       h0, hbuf, out);

    dimkt_y<<<(BB * SS) / 4, 256, 0, stream>>>(xh, hbuf, out);
}

// Round 15
// 481.123 us; speedup vs baseline: 1.1028x; 1.0165x over previous
//
#include <hip/hip_runtime.h>

// Problem constants
#define BB 256
#define SS 512
#define DD 128

// fast sigmoid/tanh via v_rcp_f32 (approx rcp) — avoids IEEE division
__device__ __forceinline__ float sigf(float v) {
    return __builtin_amdgcn_rcpf(1.0f + __expf(-v));
}
__device__ __forceinline__ float tanhf_(float v) {
    return 1.0f - 2.0f * __builtin_amdgcn_rcpf(__expf(2.0f * v) + 1.0f);
}

// Barrier that waits ONLY on LDS ops (lgkmcnt): global prefetches stay in
// flight across it (r9 win). No sched_barrier (r11 win).
__device__ __forceinline__ void lds_barrier() {
    asm volatile("s_waitcnt lgkmcnt(0)" ::: "memory");
    __builtin_amdgcn_s_barrier();
}

typedef _Float16 f16x2 __attribute__((ext_vector_type(2)));
typedef _Float16 f16x8 __attribute__((ext_vector_type(8)));
typedef float    f32x4 __attribute__((ext_vector_type(4)));

#define MFMA16(A, B, C) __builtin_amdgcn_mfma_f32_16x16x32_f16((A), (B), (C), 0, 0, 0)

// ---------------------------------------------------------------------------
// Kernel P: merged prep = tables (blocks 0..207) + f16 conversions (rest).
//   Independent work merged to save one dispatch gap (r14: non-scan is now
//   a co-equal target and includes ~several launch gaps).
// ---------------------------------------------------------------------------
#define N_EQ  (20000 * 128)
#define N_EC  (2000 * 128)
#define N_EQD (101 * 128)
#define N_ECD (101 * 128)
#define N_WXT (512 * 128)
#define N_WS  (128 * 128)
#define N_CVT (N_EQ + N_EC + N_EQD + N_ECD + N_WXT + 2 * N_WS)
#define TBL_BLOCKS 208
#define CVT_BLOCKS ((N_CVT + 255) / 256)

__global__ __launch_bounds__(256) void dimkt_prep(
    // tables inputs
    const float* __restrict__ E_corr, const float* __restrict__ E_qd,
    const float* __restrict__ E_cd,
    const float* __restrict__ W_ki, const float* __restrict__ W_p1,
    const float* __restrict__ W_p2,
    const float* __restrict__ b_ki, const float* __restrict__ b_p1,
    const float* __restrict__ b_p2,
    float* __restrict__ Ck, float* __restrict__ Cp1, float* __restrict__ Cp2,
    float* __restrict__ Qk, float* __restrict__ Cdk,
    // cvt inputs
    const float* __restrict__ E_q, const float* __restrict__ E_c,
    const float* __restrict__ Wx,
    const float* __restrict__ W_s1, const float* __restrict__ W_s2,
    _Float16* __restrict__ E_qh, _Float16* __restrict__ E_ch,
    _Float16* __restrict__ E_qdh, _Float16* __restrict__ E_cdh,
    _Float16* __restrict__ WxTh,
    _Float16* __restrict__ Ws1T, _Float16* __restrict__ Ws2T)
{
    if (blockIdx.x < TBL_BLOCKS) {
        // ---- tables: fold corr/qd/cd embedding matmul parts -----------------
        if (threadIdx.x >= 128) return;
        __shared__ float e[128];
        const int r = blockIdx.x;
        const int j = threadIdx.x;
        const float *emb, *W, *bias;
        float* op;
        if (r < 2)        { emb = E_corr + r * 128;        W = W_ki + 128 * 128; bias = b_ki;    op = Ck  + r * 128; }
        else if (r < 4)   { emb = E_corr + (r - 2) * 128;  W = W_p1 + 128 * 128; bias = b_p1;    op = Cp1 + (r - 2) * 128; }
        else if (r < 6)   { emb = E_corr + (r - 4) * 128;  W = W_p2 + 128 * 128; bias = b_p2;    op = Cp2 + (r - 4) * 128; }
        else if (r < 107) { emb = E_qd   + (r - 6) * 128;  W = W_ki + 256 * 128; bias = nullptr; op = Qk  + (r - 6) * 128; }
        else              { emb = E_cd   + (r - 107) * 128; W = W_ki + 384 * 128; bias = nullptr; op = Cdk + (r - 107) * 128; }
        e[j] = emb[j];
        __syncthreads();
        float acc = bias ? bias[j] : 0.0f;
#pragma unroll 8
        for (int i = 0; i < 128; ++i) acc = fmaf(e[i], W[i * 128 + j], acc);
        op[j] = acc;
        return;
    }
    // ---- cvt: embeddings + transposed weights to f16 ------------------------
    int o = (blockIdx.x - TBL_BLOCKS) * 256 + threadIdx.x;
    if (o >= N_CVT) return;
    if (o < N_EQ) { E_qh[o] = (_Float16)E_q[o]; return; }
    o -= N_EQ;
    if (o < N_EC) { E_ch[o] = (_Float16)E_c[o]; return; }
    o -= N_EC;
    if (o < N_EQD) { E_qdh[o] = (_Float16)E_qd[o]; return; }
    o -= N_EQD;
    if (o < N_ECD) { E_cdh[o] = (_Float16)E_cd[o]; return; }
    o -= N_ECD;
    if (o < N_WXT) {                      // WxTh[n][k] = Wx[k][n]
        int n = o >> 9, k = o & 511;
        WxTh[o] = (_Float16)Wx[k * 128 + n];
        return;
    }
    o -= N_WXT;
    if (o < N_WS) {                       // Ws1T[n][k] = W_s1[k][n]
        int n = o >> 7, k = o & 127;
        Ws1T[o] = (_Float16)W_s1[k * 128 + n];
        return;
    }
    o -= N_WS;
    {
        int n = o >> 7, k = o & 127;
        Ws2T[o] = (_Float16)W_s2[k * 128 + n];
    }
}

// ---------------------------------------------------------------------------
// Kernel S: kgb[b][t][j] = Ck[corr]+Qk[qd]+Cdk[cd] (f16 stream), grid-stride.
// ---------------------------------------------------------------------------
__global__ __launch_bounds__(256) void dimkt_strm2(
    const int* __restrict__ corr_seq, const int* __restrict__ qd_seq,
    const int* __restrict__ cd_seq,
    const float* __restrict__ Ck, const float* __restrict__ Qk,
    const float* __restrict__ Cdk,
    _Float16* __restrict__ kgb)
{
    const int total = BB * SS * 64;          // f16x2 elements
    for (int v = blockIdx.x * 256 + threadIdx.x; v < total; v += 2048 * 256) {
        const int row = v >> 6;              // flat (b*S + t)
        const int j2  = (v & 63) * 2;
        const int ic  = corr_seq[row];
        const int iq  = qd_seq[row];
        const int ie  = cd_seq[row];
        f16x2 o;
        o.x = (_Float16)(Ck[ic * 128 + j2]     + Qk[iq * 128 + j2]     + Cdk[ie * 128 + j2]);
        o.y = (_Float16)(Ck[ic * 128 + j2 + 1] + Qk[iq * 128 + j2 + 1] + Cdk[ie * 128 + j2 + 1]);
        *(f16x2*)&kgb[(size_t)row * 128 + j2] = o;
    }
}

// ---------------------------------------------------------------------------
// Kernel F: FUSED feed = xgemm + x12 (r14 win — LDS tile instead of 32MB
// global re-read).
// ---------------------------------------------------------------------------
__global__ __launch_bounds__(256, 2) void dimkt_feed(
    const int* __restrict__ q_seq, const int* __restrict__ c_seq,
    const int* __restrict__ qd_seq, const int* __restrict__ cd_seq,
    const _Float16* __restrict__ E_qh, const _Float16* __restrict__ E_ch,
    const _Float16* __restrict__ E_qdh, const _Float16* __restrict__ E_cdh,
    const _Float16* __restrict__ WxTh, const float* __restrict__ bx,
    const _Float16* __restrict__ Ws1T, const _Float16* __restrict__ Ws2T,
    const float* __restrict__ b_s1, const float* __restrict__ b_s2,
    _Float16* __restrict__ xh, f16x2* __restrict__ X12)
{
    __shared__ _Float16 xt[128][136];        // padded: 272B row stride

    const int tid = threadIdx.x;
    const int wv  = tid >> 6;
    const int l   = tid & 63;
    const int lm  = l & 15;
    const int kg8 = (l >> 4) * 8;
    const int m0  = blockIdx.x * 128;
    const int rbase = m0 + wv * 32;

    // ---- stage A: xh tile --------------------------------------------------
    {
        f32x4 acc0[8], acc1[8];
#pragma unroll
        for (int c = 0; c < 8; ++c) {
            acc0[c] = (f32x4){0.f, 0.f, 0.f, 0.f};
            acc1[c] = (f32x4){0.f, 0.f, 0.f, 0.f};
        }
#pragma unroll
        for (int s = 0; s < 4; ++s) {
            const _Float16* T  = (s == 0) ? E_qh : (s == 1) ? E_ch : (s == 2) ? E_qdh : E_cdh;
            const int*      sq = (s == 0) ? q_seq : (s == 1) ? c_seq : (s == 2) ? qd_seq : cd_seq;
            const int i0 = sq[rbase + lm];
            const int i1 = sq[rbase + 16 + lm];
            const _Float16* a0p = T + (size_t)i0 * 128 + kg8;
            const _Float16* a1p = T + (size_t)i1 * 128 + kg8;
#pragma unroll
            for (int kk = 0; kk < 4; ++kk) {
                const f16x8 a0 = *(const f16x8*)(a0p + kk * 32);
                const f16x8 a1 = *(const f16x8*)(a1p + kk * 32);
#pragma unroll
                for (int c = 0; c < 8; ++c) {
                    const f16x8 bf = *(const f16x8*)&WxTh[(size_t)(c * 16 + lm) * 512
                                                          + s * 128 + kk * 32 + kg8];
                    acc0[c] = MFMA16(a0, bf, acc0[c]);
                    acc1[c] = MFMA16(a1, bf, acc1[c]);
                }
            }
        }
#pragma unroll
        for (int c = 0; c < 8; ++c) {
            const int col = c * 16 + lm;
            const float bxv = bx[col];
#pragma unroll
            for (int r = 0; r < 4; ++r) {
                const int lr = wv * 32 + (l >> 4) * 4 + r;   // local row
                _Float16 v0 = (_Float16)(acc0[c][r] + bxv);
                _Float16 v1 = (_Float16)(acc1[c][r] + bxv);
                xh[(size_t)(m0 + lr) * 128 + col]      = v0;
                xh[(size_t)(m0 + lr + 16) * 128 + col] = v1;
                xt[lr][col]      = v0;
                xt[lr + 16][col] = v1;
            }
        }
    }
    __syncthreads();

    // ---- stage B: X1/X2 from the LDS tile ----------------------------------
    {
        f32x4 acc0[16], acc1[16];
#pragma unroll
        for (int c = 0; c < 16; ++c) {
            acc0[c] = (f32x4){0.f, 0.f, 0.f, 0.f};
            acc1[c] = (f32x4){0.f, 0.f, 0.f, 0.f};
        }
#pragma unroll
        for (int kk = 0; kk < 4; ++kk) {
            const f16x8 a0 = *(const f16x8*)&xt[wv * 32 + lm][kk * 32 + kg8];
            const f16x8 a1 = *(const f16x8*)&xt[wv * 32 + 16 + lm][kk * 32 + kg8];
#pragma unroll
            for (int c = 0; c < 16; ++c) {
                const _Float16* BT = (c < 8) ? Ws1T : Ws2T;
                const f16x8 bf = *(const f16x8*)&BT[(size_t)((c & 7) * 16 + lm) * 128
                                                    + kk * 32 + kg8];
                acc0[c] = MFMA16(a0, bf, acc0[c]);
                acc1[c] = MFMA16(a1, bf, acc1[c]);
            }
        }
#pragma unroll
        for (int c = 0; c < 8; ++c) {
            const int col = c * 16 + lm;
            const float bv1 = b_s1[col];
            const float bv2 = b_s2[col];
#pragma unroll
            for (int r = 0; r < 4; ++r) {
                const int row0 = rbase + (l >> 4) * 4 + r;
                f16x2 v0, v1;
                v0.x = (_Float16)(acc0[c][r] + bv1);
                v0.y = (_Float16)(acc0[c + 8][r] + bv2);
                v1.x = (_Float16)(acc1[c][r] + bv1);
                v1.y = (_Float16)(acc1[c + 8][r] + bv2);
                X12[(size_t)row0 * 128 + col]        = v0;
                X12[(size_t)(row0 + 16) * 128 + col] = v1;
            }
        }
    }
}

// ---------------------------------------------------------------------------
// helpers: load one B-fragment of a weight matrix (16x16x32 f16 MFMA),
// plain and negated (negation folds a1 = X1 - h@Ws1 into the MFMA sum).
// ---------------------------------------------------------------------------
__device__ __forceinline__ f16x8 load_wfrag(const float* __restrict__ W,
                                            int kbase, int j) {
    f16x8 r;
#pragma unroll
    for (int e = 0; e < 8; ++e) r[e] = (_Float16)W[(kbase + e) * DD + j];
    return r;
}
__device__ __forceinline__ f16x8 load_wfrag_neg(const float* __restrict__ W,
                                                int kbase, int j) {
    f16x8 r;
#pragma unroll
    for (int e = 0; e < 8; ++e) r[e] = (_Float16)(-W[(kbase + e) * DD + j]);
    return r;
}

// ---------------------------------------------------------------------------
// Kernel C: sequential scan, v14 = r14 (best 356-359us) + setprio + unroll 4.
//   Model: 1680cy/step = MFMA pipe 640/SIMD (fixed) + VALU ~670 + chain ~700,
//   partially overlapped. setprio(1) around MFMA clusters (T5 — predicted
//   null in lockstep, included to falsify); unroll 4 trims loop/rotation.
// ---------------------------------------------------------------------------
__global__ __launch_bounds__(512, 2) void dimkt_scan(
    const f16x2* __restrict__ X12, const _Float16* __restrict__ kgb,
    const int* __restrict__ corr_seq,
    const float* __restrict__ Cp1f, const float* __restrict__ Cp2f,
    const float* __restrict__ W_s1, const float* __restrict__ W_s2,
    const float* __restrict__ W_p1, const float* __restrict__ W_p2,
    const float* __restrict__ W_ki,
    const float* __restrict__ h0, _Float16* __restrict__ hb,
    float* __restrict__ out)
{
    __shared__ __align__(16) _Float16 h_h[128];
    __shared__ __align__(16) _Float16 s_h[128];

    const int tid  = threadIdx.x;
    const int b    = blockIdx.x;
    const int wv   = tid >> 6;
    const int l    = tid & 63;
    const int kgrp = l >> 4;
    const int j    = wv * 16 + (l & 15);
    const int base = b * SS;

    // --- 20 named weight B-fragments (w1/w2 negated) -------------------------
    const int kb = kgrp * 8;
    const f16x8 w1f0 = load_wfrag_neg(W_s1,  0 + kb, j);
    const f16x8 w1f1 = load_wfrag_neg(W_s1, 32 + kb, j);
    const f16x8 w1f2 = load_wfrag_neg(W_s1, 64 + kb, j);
    const f16x8 w1f3 = load_wfrag_neg(W_s1, 96 + kb, j);
    const f16x8 w2f0 = load_wfrag_neg(W_s2,  0 + kb, j);
    const f16x8 w2f1 = load_wfrag_neg(W_s2, 32 + kb, j);
    const f16x8 w2f2 = load_wfrag_neg(W_s2, 64 + kb, j);
    const f16x8 w2f3 = load_wfrag_neg(W_s2, 96 + kb, j);
    const f16x8 wkf0 = load_wfrag(W_ki,  0 + kb, j);
    const f16x8 wkf1 = load_wfrag(W_ki, 32 + kb, j);
    const f16x8 wkf2 = load_wfrag(W_ki, 64 + kb, j);
    const f16x8 wkf3 = load_wfrag(W_ki, 96 + kb, j);
    const f16x8 p1f0 = load_wfrag(W_p1,  0 + kb, j);
    const f16x8 p1f1 = load_wfrag(W_p1, 32 + kb, j);
    const f16x8 p1f2 = load_wfrag(W_p1, 64 + kb, j);
    const f16x8 p1f3 = load_wfrag(W_p1, 96 + kb, j);
    const f16x8 p2f0 = load_wfrag(W_p2,  0 + kb, j);
    const f16x8 p2f1 = load_wfrag(W_p2, 32 + kb, j);
    const f16x8 p2f2 = load_wfrag(W_p2, 64 + kb, j);
    const f16x8 p2f3 = load_wfrag(W_p2, 96 + kb, j);

    // --- Cp register residence (2 rows only) ---------------------------------
    const float cp1r0 = Cp1f[j],       cp2r0 = Cp2f[j];
    const float cp1r1 = Cp1f[128 + j], cp2r1 = Cp2f[128 + j];

    // --- init ----------------------------------------------------------------
    float h = h0[b * DD + j];
    if (kgrp == 0) h_h[j] = (_Float16)h;

    f16x2    X12v = X12[(size_t)base * DD + j];
    _Float16 kgt  = kgb[(size_t)base * DD + j];
    int ic0 = __builtin_amdgcn_readfirstlane(corr_seq[base]);
    float tcp1 = ic0 ? cp1r1 : cp1r0;
    float tcp2 = ic0 ? cp2r1 : cp2r0;
    int icN = __builtin_amdgcn_readfirstlane(corr_seq[base + 1]);
    lds_barrier();

    const f32x4 z = {0.f, 0.f, 0.f, 0.f};

#pragma unroll 4
    for (int t = 0; t < 511; ++t) {
        // ---- phase 1: a1 = X1 - h@Ws1 (neg-folded), a2 likewise, kg = h@Wki -
        const f16x8 hA0 = *(const f16x8*)&h_h[ 0 + kb];
        const f16x8 hA1 = *(const f16x8*)&h_h[32 + kb];
        const f16x8 hA2 = *(const f16x8*)&h_h[64 + kb];
        const f16x8 hA3 = *(const f16x8*)&h_h[96 + kb];

        __builtin_amdgcn_s_setprio(1);
        f32x4 c1a = MFMA16(hA0, w1f0, z);
        f32x4 c2a = MFMA16(hA0, w2f0, z);
        f32x4 cka = MFMA16(hA0, wkf0, z);
        f32x4 c1b = MFMA16(hA2, w1f2, z);
        f32x4 c2b = MFMA16(hA2, w2f2, z);
        f32x4 ckb = MFMA16(hA2, wkf2, z);
        c1a = MFMA16(hA1, w1f1, c1a);
        c2a = MFMA16(hA1, w2f1, c2a);
        cka = MFMA16(hA1, wkf1, cka);
        c1b = MFMA16(hA3, w1f3, c1b);
        c2b = MFMA16(hA3, w2f3, c2b);
        ckb = MFMA16(hA3, wkf3, ckb);
        __builtin_amdgcn_s_setprio(0);

        float a1 = (float)X12v.x + c1a[0] + c1b[0];    // weights negated
        float a2 = (float)X12v.y + c2a[0] + c2b[0];
        float sdf = sigf(a1) * tanhf_(a2);
        if (kgrp == 0) s_h[j] = (_Float16)sdf;         // write ASAP
        float kg = cka[0] + ckb[0] + (float)kgt;
        lds_barrier();     // B1

        // ---- phase 2: p1 = sdf@Wp1, p2 = sdf@Wp2; h update ------------------
        const f16x8 sA0 = *(const f16x8*)&s_h[ 0 + kb];
        const f16x8 sA1 = *(const f16x8*)&s_h[32 + kb];
        const f16x8 sA2 = *(const f16x8*)&s_h[64 + kb];
        const f16x8 sA3 = *(const f16x8*)&s_h[96 + kb];

        __builtin_amdgcn_s_setprio(1);
        f32x4 q1a = MFMA16(sA0, p1f0, z);
        f32x4 q2a = MFMA16(sA0, p2f0, z);
        f32x4 q1b = MFMA16(sA2, p1f2, z);
        f32x4 q2b = MFMA16(sA2, p2f2, z);
        q1a = MFMA16(sA1, p1f1, q1a);
        q2a = MFMA16(sA1, p2f1, q2a);
        q1b = MFMA16(sA3, p1f3, q1b);
        q2b = MFMA16(sA3, p2f3, q2b);
        __builtin_amdgcn_s_setprio(0);

        // g's sigmoid: trans issue hides under phase-2 MFMA latency
        float g = sigf(kg);

        // ---- stream prefetch for t+1 (phase-2 region — r11/r12 placement) --
        const size_t noff = (size_t)(base + t + 1) * DD + j;
        f16x2    nX12 = X12[noff];
        _Float16 nkgt = kgb[noff];
        float ncp1 = icN ? cp1r1 : cp1r0;
        float ncp2 = icN ? cp2r1 : cp2r0;
        const int n2 = base + ((t + 2 > 511) ? 511 : (t + 2));
        int icN2 = __builtin_amdgcn_readfirstlane(corr_seq[n2]);

        float pka = sigf(q1a[0] + q1b[0] + tcp1)
                  * tanhf_(q2a[0] + q2b[0] + tcp2);
        float hn  = fmaf(g, h - pka, pka);
        _Float16 hn16 = (_Float16)hn;
        if (kgrp == 0) {
            h_h[j] = hn16;                            // LDS write ASAP
            hb[(size_t)(base + t) * DD + j] = hn16;   // fire-and-forget store
        }

        h = hn;
        X12v = nX12; kgt = nkgt; tcp1 = ncp1; tcp2 = ncp2; icN = icN2;
        lds_barrier();     // B2
    }

    if (tid == 0) out[base + 511] = 0.0f;
}

// ---------------------------------------------------------------------------
// Kernel D: y[b][t] = sigmoid(dot(xh[b][t+1], hb[b][t])), t = 0..510.
// ---------------------------------------------------------------------------
__global__ __launch_bounds__(256) void dimkt_y(
    const _Float16* __restrict__ xh, const _Float16* __restrict__ hb,
    float* __restrict__ out)
{
    const int o = blockIdx.x * 4 + (threadIdx.x >> 6);   // flat (b,t)
    const int l = threadIdx.x & 63;
    const int b = o >> 9;
    const int t = o & 511;
    if (t == 511) return;   // handled by scan
    f16x2 xv = *(const f16x2*)&xh[((size_t)(b * SS + t + 1)) * DD + 2 * l];
    f16x2 hv = *(const f16x2*)&hb[((size_t)(b * SS + t)) * DD + 2 * l];
    float s = (float)xv.x * (float)hv.x + (float)xv.y * (float)hv.y;
    s += __shfl_xor(s, 1);  s += __shfl_xor(s, 2);  s += __shfl_xor(s, 4);
    s += __shfl_xor(s, 8);  s += __shfl_xor(s, 16); s += __shfl_xor(s, 32);
    if (l == 0) out[b * SS + t] = sigf(s);
}

// ---------------------------------------------------------------------------
extern "C" void kernel_launch(void* const* d_in, const int* in_sizes, int n_in,
                              void* d_out, int out_size, void* d_ws, size_t ws_size,
                              hipStream_t stream) {
    const int*   q_seq    = (const int*)d_in[0];
    const int*   c_seq    = (const int*)d_in[1];
    const int*   qd_seq   = (const int*)d_in[2];
    const int*   cd_seq   = (const int*)d_in[3];
    const int*   corr_seq = (const int*)d_in[4];
    const float* E_q    = (const float*)d_in[5];
    const float* E_c    = (const float*)d_in[6];
    const float* E_qd   = (const float*)d_in[7];
    const float* E_cd   = (const float*)d_in[8];
    const float* E_corr = (const float*)d_in[9];
    const float* Wx     = (const float*)d_in[10];
    const float* bx     = (const float*)d_in[11];
    const float* W_s1   = (const float*)d_in[12];
    const float* b_s1   = (const float*)d_in[13];
    const float* W_s2   = (const float*)d_in[14];
    const float* b_s2   = (const float*)d_in[15];
    const float* W_p1   = (const float*)d_in[16];
    const float* b_p1   = (const float*)d_in[17];
    const float* W_p2   = (const float*)d_in[18];
    const float* b_p2   = (const float*)d_in[19];
    const float* W_ki   = (const float*)d_in[20];
    const float* b_ki   = (const float*)d_in[21];
    const float* h0     = (const float*)d_in[22];
    float* out = (float*)d_out;

    // ---- workspace carve-up (same budget as r14) ----------------------------
    float* Ck   = (float*)d_ws;                       // 2 x 128
    float* Cp1  = Ck  + 256;
    float* Cp2  = Cp1 + 256;
    float* Qk   = Cp2 + 256;                          // 101 x 128
    float* Cdk  = Qk  + 101 * 128;                    // 101 x 128
    _Float16* pool  = (_Float16*)((char*)d_ws + (size_t)131072);
    const size_t NBT = (size_t)BB * SS * DD;          // 16,777,216
    _Float16* xh    = pool;                           // f16 x          (32MB)
    f16x2*    X12   = (f16x2*)(xh + NBT);             // {X1,X2} f16x2  (64MB)
    _Float16* hbuf  = (_Float16*)(X12 + NBT);         // f16 h states   (32MB)
    _Float16* kgb   = hbuf + NBT;                     // kg table strm  (32MB)
    _Float16* E_qh  = kgb + NBT;
    _Float16* E_ch  = E_qh + N_EQ;
    _Float16* E_qdh = E_ch + N_EC;
    _Float16* E_cdh = E_qdh + N_EQD;
    _Float16* WxTh  = E_cdh + N_ECD;                  // 128 x 512 (transposed)
    _Float16* Ws1T  = WxTh + N_WXT;                   // 128 x 128 (transposed)
    _Float16* Ws2T  = Ws1T + N_WS;

    dimkt_prep<<<TBL_BLOCKS + CVT_BLOCKS, 256, 0, stream>>>(
        E_corr, E_qd, E_cd, W_ki, W_p1, W_p2, b_ki, b_p1, b_p2,
        Ck, Cp1, Cp2, Qk, Cdk,
        E_q, E_c, Wx, W_s1, W_s2,
        E_qh, E_ch, E_qdh, E_cdh, WxTh, Ws1T, Ws2T);

    dimkt_strm2<<<2048, 256, 0, stream>>>(corr_seq, qd_seq, cd_seq,
                                          Ck, Qk, Cdk, kgb);

    dimkt_feed<<<(BB * SS) / 128, 256, 0, stream>>>(
        q_seq, c_seq, qd_seq, cd_seq,
        E_qh, E_ch, E_qdh, E_cdh, WxTh, bx,
        Ws1T, Ws2T, b_s1, b_s2, xh, X12);

    dimkt_scan<<<BB, 512, 0, stream>>>(X12, kgb, corr_seq, Cp1, Cp2,
                                       W_s1, W_s2, W_p1, W_p2, W_ki,
                                       h0, hbuf, out);

    dimkt_y<<<(BB * SS) / 4, 256, 0, stream>>>(xh, hbuf, out);
}